// Round 6
// baseline (1863.258 us; speedup 1.0000x reference)
//
#include <hip/hip_runtime.h>
#include <hip/hip_bf16.h>

#define N_NODES 10000
#define N_EDGES 320000
#define D_NODE 32
#define D_RAD 8
#define D_SPH 9
#define LAT 64
#define NHEAD 8
#define NL 2
#define GEN_W 280
#define WN_ENV 24

#define RS136 0.08574929257125442f   // 136^-0.5
#define RS8   0.35355339059327373f   // 8^-0.5

static_assert(N_EDGES % 4 == 0, "edge quads");

__device__ __forceinline__ int irrep_of(int d){ return (d==0)?0:((d<4)?1:2); }

__device__ __forceinline__ float wave_sum(float v){
  #pragma unroll
  for (int off=32; off; off>>=1) v += __shfl_xor(v, off);
  return v;
}

__device__ __forceinline__ void atomicMaxF(float* addr, float v){
  if (v >= 0.f) atomicMax((int*)addr, __float_as_int(v));
  else          atomicMin((unsigned int*)addr, __float_as_uint(v));
}

__device__ __forceinline__ float f4g(const float4& v, int i){
  return (i==0)?v.x:((i==1)?v.y:((i==2)?v.z:v.w));
}

// K1: pn = na@W_node, pc = na@W_center
__global__ void k_node_proj(const float* __restrict__ na,
                            const float* __restrict__ Wn,
                            const float* __restrict__ Wc,
                            float* __restrict__ pn, float* __restrict__ pc){
  int idx = blockIdx.x*blockDim.x + threadIdx.x;
  int n = idx >> 6, j = idx & 63;
  if (n >= N_NODES) return;
  float an = 0.f, ac = 0.f;
  #pragma unroll
  for (int k = 0; k < D_NODE; k++){
    float a = na[n*D_NODE + k];
    an += a * Wn[k*LAT + j];
    ac += a * Wc[k*LAT + j];
  }
  pn[idx] = an; pc[idx] = ac;
}

// K2: pe = pn[nb] * (phi@W_edge); m_node = segsum(pe). E=4, We in LDS.
__global__ void __launch_bounds__(256,4) k_edge_msg(const float* __restrict__ phi,
                           const float* __restrict__ We,
                           const int* __restrict__ ec, const int* __restrict__ en,
                           const float* __restrict__ pn, float* __restrict__ mnode){
  __shared__ float swe[8*64];
  for (int i = threadIdx.x; i < 8*64; i += 256) swe[i] = We[i];
  __syncthreads();
  const int j = threadIdx.x & 63;
  int wid = blockIdx.x*4 + (threadIdx.x >> 6);
  int nw  = gridDim.x*4;
  for (int p = wid; p < N_EDGES/4; p += nw){
    const int eb = p*4;
    int4 cv = *(const int4*)(ec + eb);
    int4 nv = *(const int4*)(en + eb);
    int c0 = __builtin_amdgcn_readfirstlane(cv.x);
    int c1 = __builtin_amdgcn_readfirstlane(cv.y);
    int c2 = __builtin_amdgcn_readfirstlane(cv.z);
    int c3 = __builtin_amdgcn_readfirstlane(cv.w);
    int n0 = __builtin_amdgcn_readfirstlane(nv.x);
    int n1 = __builtin_amdgcn_readfirstlane(nv.y);
    int n2 = __builtin_amdgcn_readfirstlane(nv.z);
    int n3 = __builtin_amdgcn_readfirstlane(nv.w);
    const float4* ph = (const float4*)(phi + (long)eb*D_RAD);
    float d0=0.f, d1=0.f, d2=0.f, d3=0.f;
    #pragma unroll
    for (int kk = 0; kk < 2; kk++){
      float4 p0=ph[kk], p1=ph[2+kk], p2=ph[4+kk], p3=ph[6+kk];
      #pragma unroll
      for (int i = 0; i < 4; i++){
        float u = swe[(kk*4+i)*64 + j];
        d0+=f4g(p0,i)*u; d1+=f4g(p1,i)*u; d2+=f4g(p2,i)*u; d3+=f4g(p3,i)*u;
      }
    }
    atomicAdd(&mnode[(long)c0*LAT + j], pn[(long)n0*LAT + j] * d0);
    atomicAdd(&mnode[(long)c1*LAT + j], pn[(long)n1*LAT + j] * d1);
    atomicAdd(&mnode[(long)c2*LAT + j], pn[(long)n2*LAT + j] * d2);
    atomicAdd(&mnode[(long)c3*LAT + j], pn[(long)n3*LAT + j] * d3);
  }
}

// K3: h0 = h = LN([pc, m_node]@W_concat)
__global__ void k_node_h(const float* __restrict__ pc, const float* __restrict__ mnode,
                         const float* __restrict__ Wcat,
                         const float* __restrict__ g, const float* __restrict__ b,
                         float* __restrict__ h0, float* __restrict__ h){
  int n = blockIdx.x*(blockDim.x >> 6) + (threadIdx.x >> 6);
  int j = threadIdx.x & 63;
  if (n >= N_NODES) return;
  float acc = 0.f;
  for (int k = 0; k < LAT; k++) acc += pc[n*LAT + k] * Wcat[k*LAT + j];
  for (int k = 0; k < LAT; k++) acc += mnode[n*LAT + k] * Wcat[(LAT + k)*LAT + j];
  float mu = wave_sum(acc) * (1.f/64.f);
  float va = wave_sum(acc*acc) * (1.f/64.f) - mu*mu;
  float v = (acc - mu) * rsqrtf(va + 1e-5f) * g[j] + b[j];
  h0[n*LAT + j] = v; h[n*LAT + j] = v;
}

// K3b: P0[n] = [ h0@Wtcat[0:64]*RS136 | h0@Wtcat[64:128]*RS136 | h0@Wh0*0.125 ]
__global__ void __launch_bounds__(256) k_pre0(const float* __restrict__ h0,
                       const float* __restrict__ Wtcat, const float* __restrict__ Wh0,
                       float* __restrict__ P0){
  __shared__ float sw[64*152];
  for (int i = threadIdx.x; i < 64*152; i += 256){
    int k = i / 152, c = i - k*152;
    float v;
    if (c < 64)       v = Wtcat[k*64 + c] * RS136;
    else if (c < 128) v = Wtcat[(64 + k)*64 + (c - 64)] * RS136;
    else              v = Wh0[k*24 + (c - 128)] * 0.125f;
    sw[i] = v;
  }
  __syncthreads();
  const int j = threadIdx.x & 63;
  int wid = blockIdx.x*4 + (threadIdx.x >> 6);
  int nw = gridDim.x*4;
  for (int n = wid; n < N_NODES; n += nw){
    const float4* xp = (const float4*)(h0 + (long)n*LAT);
    float a0=0.f, a1=0.f, a2=0.f;
    #pragma unroll 2
    for (int kk = 0; kk < 16; kk++){
      float4 xv = xp[kk];
      #pragma unroll
      for (int i = 0; i < 4; i++){
        float xi = f4g(xv, i);
        const float* w = sw + (kk*4+i)*152;
        a0 += xi * w[j];
        a1 += xi * w[64 + j];
        if (j < 24) a2 += xi * w[128 + j];
      }
    }
    P0[(long)n*152 + j] = a0;
    P0[(long)n*152 + 64 + j] = a1;
    if (j < 24) P0[(long)n*152 + 128 + j] = a2;
  }
}

// generic per-node GEMM: out[n][c] = scale * sum_k in[n][k]*W[k*ldw+c], c<C
template<int C>
__global__ void __launch_bounds__(256) k_node_mm(const float* __restrict__ in,
    const float* __restrict__ W, int ldw, float scale, float* __restrict__ out){
  __shared__ float sw[64*C];
  for (int i = threadIdx.x; i < 64*C; i += 256){
    int k = i / C, c = i - k*C;
    sw[i] = W[k*ldw + c] * scale;
  }
  __syncthreads();
  const int j = threadIdx.x & 63;
  constexpr int G = (C + 63)/64;
  int wid = blockIdx.x*4 + (threadIdx.x >> 6);
  int nw = gridDim.x*4;
  for (int n = wid; n < N_NODES; n += nw){
    const float4* xp = (const float4*)(in + (long)n*LAT);
    float acc[G];
    #pragma unroll
    for (int g = 0; g < G; g++) acc[g] = 0.f;
    #pragma unroll 2
    for (int kk = 0; kk < 16; kk++){
      float4 xv = xp[kk];
      #pragma unroll
      for (int i = 0; i < 4; i++){
        float xi = f4g(xv, i);
        int k = kk*4 + i;
        #pragma unroll
        for (int g = 0; g < G; g++){
          int c = g*64 + j;
          if (c < C) acc[g] += xi * sw[k*C + c];
        }
      }
    }
    #pragma unroll
    for (int g = 0; g < G; g++){
      int c = g*64 + j;
      if (c < C) out[(long)n*C + c] = acc[g];
    }
  }
}

// K4: fused tij. Phase1: t = LN(tA[c]+tB[nb]+phi@W3); phase2: edge_out=t@Wtij/8,
// w0 = (t@Wt0)*hh0[nb]*0.125 -> Xacc. k-packed float4 LDS weights (b128 reads).
// LDS 28KB -> 5 blk/CU.
__global__ void __launch_bounds__(256,5) k_tij(
    const float* __restrict__ P0, const float* __restrict__ phi,
    const float* __restrict__ sph,
    const float* __restrict__ Wtcat,
    const float* __restrict__ lg, const float* __restrict__ lb,
    const float* __restrict__ Wtij, const float* __restrict__ Wt0,
    const int* __restrict__ ec, const int* __restrict__ en,
    float* __restrict__ T, float* __restrict__ Xacc,
    float* __restrict__ edge_out){
  __shared__ float4 sW34[2*64];
  __shared__ float4 swij4[16*64];
  __shared__ float4 sw04[16*24];
  __shared__ float tst[4][4][64];
  for (int i = threadIdx.x; i < 2*64; i += 256){
    int kk = i >> 6, j2 = i & 63;
    sW34[i] = make_float4(Wtcat[(128+4*kk+0)*64 + j2]*RS136,
                          Wtcat[(128+4*kk+1)*64 + j2]*RS136,
                          Wtcat[(128+4*kk+2)*64 + j2]*RS136,
                          Wtcat[(128+4*kk+3)*64 + j2]*RS136);
  }
  for (int i = threadIdx.x; i < 16*64; i += 256){
    int kk = i >> 6, j2 = i & 63;
    swij4[i] = make_float4(Wtij[(4*kk+0)*64 + j2], Wtij[(4*kk+1)*64 + j2],
                           Wtij[(4*kk+2)*64 + j2], Wtij[(4*kk+3)*64 + j2]);
  }
  for (int i = threadIdx.x; i < 16*24; i += 256){
    int kk = i / 24, c = i - kk*24;
    sw04[i] = make_float4(Wt0[(4*kk+0)*24 + c], Wt0[(4*kk+1)*24 + c],
                          Wt0[(4*kk+2)*24 + c], Wt0[(4*kk+3)*24 + c]);
  }
  __syncthreads();
  const int j = threadIdx.x & 63, lw = threadIdx.x >> 6;
  const float gj = lg[j], bj = lb[j];
  const int jc = (j < 24) ? j : 0;
  int wid = blockIdx.x*4 + lw;
  int nw  = gridDim.x*4;
  for (int p = wid; p < N_EDGES/4; p += nw){
    const int eb = p*4;
    int4 cv = *(const int4*)(ec + eb);
    int4 nv = *(const int4*)(en + eb);
    int ccs[4], nns[4];
    ccs[0] = __builtin_amdgcn_readfirstlane(cv.x);
    ccs[1] = __builtin_amdgcn_readfirstlane(cv.y);
    ccs[2] = __builtin_amdgcn_readfirstlane(cv.z);
    ccs[3] = __builtin_amdgcn_readfirstlane(cv.w);
    nns[0] = __builtin_amdgcn_readfirstlane(nv.x);
    nns[1] = __builtin_amdgcn_readfirstlane(nv.y);
    nns[2] = __builtin_amdgcn_readfirstlane(nv.z);
    nns[3] = __builtin_amdgcn_readfirstlane(nv.w);
    // phase 1: gather + phi GEMV + LN
    float a[4], hh[4];
    #pragma unroll
    for (int x = 0; x < 4; x++){
      a[x]  = P0[(long)ccs[x]*152 + j] + P0[(long)nns[x]*152 + 64 + j];
      hh[x] = P0[(long)nns[x]*152 + 128 + jc];
    }
    const float4* ph = (const float4*)(phi + (long)eb*D_RAD);
    #pragma unroll
    for (int kk = 0; kk < 2; kk++){
      float4 p0=ph[kk], p1=ph[2+kk], p2=ph[4+kk], p3=ph[6+kk];
      float4 u4 = sW34[kk*64 + j];
      #pragma unroll
      for (int i = 0; i < 4; i++){
        float u = f4g(u4, i);
        a[0]+=f4g(p0,i)*u; a[1]+=f4g(p1,i)*u; a[2]+=f4g(p2,i)*u; a[3]+=f4g(p3,i)*u;
      }
    }
    #pragma unroll
    for (int x = 0; x < 4; x++){
      float acc = a[x];
      float mu = wave_sum(acc) * (1.f/64.f);
      float va = wave_sum(acc*acc) * (1.f/64.f) - mu*mu;
      float t = (acc - mu) * rsqrtf(va + 1e-5f) * gj + bj;
      T[(long)(eb+x)*LAT + j] = t;
      tst[lw][x][j] = t;
    }
    // phase 2 (tst same-wave DS: in-order, no fence needed)
    float eo[4]={0,0,0,0}, av[4]={0,0,0,0};
    #pragma unroll 2
    for (int kk = 0; kk < 16; kk++){
      float4 tv0 = *(const float4*)&tst[lw][0][kk*4];
      float4 tv1 = *(const float4*)&tst[lw][1][kk*4];
      float4 tv2 = *(const float4*)&tst[lw][2][kk*4];
      float4 tv3 = *(const float4*)&tst[lw][3][kk*4];
      float4 u4 = swij4[kk*64 + j];
      float4 w4 = sw04[kk*24 + jc];
      #pragma unroll
      for (int i = 0; i < 4; i++){
        float u = f4g(u4, i), w = f4g(w4, i);
        eo[0]+=f4g(tv0,i)*u; av[0]+=f4g(tv0,i)*w;
        eo[1]+=f4g(tv1,i)*u; av[1]+=f4g(tv1,i)*w;
        eo[2]+=f4g(tv2,i)*u; av[2]+=f4g(tv2,i)*w;
        eo[3]+=f4g(tv3,i)*u; av[3]+=f4g(tv3,i)*w;
      }
    }
    float w0s[4];
    #pragma unroll
    for (int x = 0; x < 4; x++){
      edge_out[(long)(eb+x)*LAT + j] = eo[x] * 0.125f;
      w0s[x] = av[x] * hh[x] * 0.125f;
    }
    #pragma unroll
    for (int x = 0; x < 4; x++){
      #pragma unroll
      for (int rep = 0; rep < 2; rep++){
        int tt = j + rep*64;
        int m = tt/9, d = tt - (tt/9)*9;
        int wi = (tt < 72) ? (irrep_of(d)*NHEAD + m) : 0;
        float wv = __shfl(w0s[x], wi);
        if (tt < 72){
          atomicAdd(&Xacc[ccs[x]*72 + tt], sph[(long)(eb+x)*D_SPH + d] * wv);
        }
      }
    }
  }
}

// K5: X = so3_norm(Xacc); also zero/init per-layer accumulators (hacc/asum/amax/Xacc)
__global__ void k_node_X0(float* __restrict__ Xacc, float* __restrict__ X,
                          float* __restrict__ hacc, float* __restrict__ asum,
                          float* __restrict__ amax){
  int n = blockIdx.x*(blockDim.x >> 6) + (threadIdx.x >> 6);
  int j = threadIdx.x & 63;
  if (n >= N_NODES) return;
  float x0 = Xacc[n*72 + j];
  float x1 = (j < 8) ? Xacc[n*72 + 64 + j] : 0.f;
  float s0 = 0.f, s1 = 0.f, s2 = 0.f;
  { int d = j % 9; int k3 = irrep_of(d);
    if (k3 == 0) s0 = x0*x0; else if (k3 == 1) s1 = x0*x0; else s2 = x0*x0; }
  if (j < 8){ int d = (64 + j) % 9; int k3 = irrep_of(d);
    if (k3 == 0) s0 += x1*x1; else if (k3 == 1) s1 += x1*x1; else s2 += x1*x1; }
  s0 = wave_sum(s0); s1 = wave_sum(s1); s2 = wave_sum(s2);
  float sa = rsqrtf(s0*0.125f + 1e-5f), sb = rsqrtf(s1*0.125f + 1e-5f), sc = rsqrtf(s2*0.125f + 1e-5f);
  { int d = j % 9; int k3 = irrep_of(d);
    X[n*72 + j] = x0 * (k3==0 ? sa : (k3==1 ? sb : sc)); }
  if (j < 8){ int d = (64 + j) % 9; int k3 = irrep_of(d);
    X[n*72 + 64 + j] = x1 * (k3==0 ? sa : (k3==1 ? sb : sc)); }
  // reset accumulators for layer 0
  Xacc[n*72 + j] = 0.f;
  if (j < 8) Xacc[n*72 + 64 + j] = 0.f;
  hacc[n*LAT + j] = 0.f;
  if (j < 8){ asum[n*NHEAD + j] = 0.f; amax[n*NHEAD + j] = __uint_as_float(0xff800000u); }
}

// K6: attention logits + running max. Q = t@Wq; K gathered from Hk (prefetched).
// k-packed float4 weights -> 2 b128/kk. LDS 32KB -> 4 blk/CU.
__global__ void __launch_bounds__(256,4) k_att(const float* __restrict__ T, const float* __restrict__ Hk,
                     const float* __restrict__ Wq,
                     const int* __restrict__ ec, const int* __restrict__ en,
                     float* __restrict__ att, float* __restrict__ attmax){
  __shared__ float4 sqa[16*64], sqb[16*64];
  for (int i = threadIdx.x; i < 16*64; i += 256){
    int kk = i >> 6, j2 = i & 63;
    sqa[i] = make_float4(Wq[(4*kk+0)*128 + j2], Wq[(4*kk+1)*128 + j2],
                         Wq[(4*kk+2)*128 + j2], Wq[(4*kk+3)*128 + j2]);
    sqb[i] = make_float4(Wq[(4*kk+0)*128 + 64 + j2], Wq[(4*kk+1)*128 + 64 + j2],
                         Wq[(4*kk+2)*128 + 64 + j2], Wq[(4*kk+3)*128 + 64 + j2]);
  }
  __syncthreads();
  const int j = threadIdx.x & 63;
  int wid = blockIdx.x*4 + (threadIdx.x >> 6);
  int nw  = gridDim.x*4;
  for (int p = wid; p < N_EDGES/4; p += nw){
    const int eb = p*4;
    int4 cv = *(const int4*)(ec + eb);
    int4 nv = *(const int4*)(en + eb);
    int ccs[4], nns[4];
    ccs[0] = __builtin_amdgcn_readfirstlane(cv.x);
    ccs[1] = __builtin_amdgcn_readfirstlane(cv.y);
    ccs[2] = __builtin_amdgcn_readfirstlane(cv.z);
    ccs[3] = __builtin_amdgcn_readfirstlane(cv.w);
    nns[0] = __builtin_amdgcn_readfirstlane(nv.x);
    nns[1] = __builtin_amdgcn_readfirstlane(nv.y);
    nns[2] = __builtin_amdgcn_readfirstlane(nv.z);
    nns[3] = __builtin_amdgcn_readfirstlane(nv.w);
    // prefetch K gathers (retire under GEMV)
    float ha[4], hb[4];
    #pragma unroll
    for (int x = 0; x < 4; x++){
      ha[x] = Hk[(long)nns[x]*128 + j];
      hb[x] = Hk[(long)nns[x]*128 + 64 + j];
    }
    const float4* tp0 = (const float4*)(T + (long)(eb+0)*LAT);
    const float4* tp1 = (const float4*)(T + (long)(eb+1)*LAT);
    const float4* tp2 = (const float4*)(T + (long)(eb+2)*LAT);
    const float4* tp3 = (const float4*)(T + (long)(eb+3)*LAT);
    float qa[4]={0,0,0,0}, qb[4]={0,0,0,0};
    #pragma unroll 2
    for (int kk = 0; kk < 16; kk++){
      float4 tv[4] = {tp0[kk], tp1[kk], tp2[kk], tp3[kk]};
      float4 wa = sqa[kk*64 + j];
      float4 wb = sqb[kk*64 + j];
      #pragma unroll
      for (int i = 0; i < 4; i++){
        float q0 = f4g(wa, i), q1 = f4g(wb, i);
        #pragma unroll
        for (int x = 0; x < 4; x++){
          float tx = f4g(tv[x], i);
          qa[x] += tx*q0; qb[x] += tx*q1;
        }
      }
    }
    float pa[4], pb[4];
    #pragma unroll
    for (int x = 0; x < 4; x++){ pa[x] = qa[x]*ha[x]; pb[x] = qb[x]*hb[x]; }
    #pragma unroll
    for (int off = 8; off; off >>= 1){
      #pragma unroll
      for (int x = 0; x < 4; x++){
        pa[x] += __shfl_xor(pa[x], off);
        pb[x] += __shfl_xor(pb[x], off);
      }
    }
    if ((j & 15) == 0){
      int m = j >> 4;
      #pragma unroll
      for (int x = 0; x < 4; x++){
        float A = 4.f*pa[x], B = 4.f*pb[x];
        att[(long)(eb+x)*NHEAD + m] = A;
        att[(long)(eb+x)*NHEAD + 4 + m] = B;
        atomicMaxF(&attmax[ccs[x]*NHEAD + m], A);
        atomicMaxF(&attmax[ccs[x]*NHEAD + 4 + m], B);
      }
    }
  }
}

// K7: env = (t@Wrs[:216]) * Hw[nb]; hacc/asum/Xacc scatter in one pass.
// 1024 thr (16 waves) / 1 blk/CU. Prefetch Hw/att/attmax/sph before GEMV.
// senv stored with k3-stride 72 (disjoint bank windows -> conflict-free dq reads).
// LDS = 55296(srs) + 61440(senv) + 20480(sxn) + 2048(sev) = 139264 B.
__global__ void __launch_bounds__(1024,4) k_env(
    const float* __restrict__ T, const float* __restrict__ Hw,
    const float* __restrict__ X,
    const float* __restrict__ Wrs,
    const float* __restrict__ sph,
    const float* __restrict__ att, const float* __restrict__ attmax,
    const int* __restrict__ ec, const int* __restrict__ en,
    float* __restrict__ hacc, float* __restrict__ asum,
    float* __restrict__ Xacc){
  __shared__ float srs[64*216];
  __shared__ float senv[16][4][240];
  __shared__ float sxn[16][4][80];
  __shared__ float sev[16][32];
  for (int i = threadIdx.x; i < 64*216; i += 1024){
    int k = i / 216, c = i - k*216;
    srs[i] = Wrs[k*GEN_W + c];
  }
  __syncthreads();
  const int j = threadIdx.x & 63, lw = threadIdx.x >> 6;
  // senv write position for this lane's float4 (cols 4j..4j+3), k3-strided by 72
  int wpos = 0;
  if (j < 54){
    int c0 = 4*j;
    wpos = (c0 < 24) ? c0 : 24 + ((c0-24) >> 6)*72 + ((c0-24) & 63);
  }
  const int d0 = j - (j/9)*9, m0 = j/9;           // rep0: tt=j
  const int d1 = 1 + j, m1 = 7;                    // rep1: tt=64+j (j<8)
  int wid = blockIdx.x*16 + lw;
  int nw  = gridDim.x*16;
  for (int p = wid; p < N_EDGES/4; p += nw){
    const int eb = p*4;
    int4 cv = *(const int4*)(ec + eb);
    int4 nv = *(const int4*)(en + eb);
    int ccs[4], nns[4];
    ccs[0] = __builtin_amdgcn_readfirstlane(cv.x);
    ccs[1] = __builtin_amdgcn_readfirstlane(cv.y);
    ccs[2] = __builtin_amdgcn_readfirstlane(cv.z);
    ccs[3] = __builtin_amdgcn_readfirstlane(cv.w);
    nns[0] = __builtin_amdgcn_readfirstlane(nv.x);
    nns[1] = __builtin_amdgcn_readfirstlane(nv.y);
    nns[2] = __builtin_amdgcn_readfirstlane(nv.z);
    nns[3] = __builtin_amdgcn_readfirstlane(nv.w);
    // ---- prefetch everything the post-GEMV phase needs ----
    float4 hw4[4];
    float sp0[4], sp1[4];
    float attp = 0.f, amaxp = 0.f;
    #pragma unroll
    for (int x = 0; x < 4; x++){
      if (j < 54) hw4[x] = *(const float4*)(Hw + (long)nns[x]*216 + j*4);
      sp0[x] = sph[(long)(eb+x)*D_SPH + d0];
      if (j < 8) sp1[x] = sph[(long)(eb+x)*D_SPH + d1];
      const float* Xr = X + (long)nns[x]*72;
      sxn[lw][x][j] = Xr[j];
      if (j < 8) sxn[lw][x][64 + j] = Xr[64 + j];
    }
    if (j < 32){
      int x = j >> 3, m = j & 7;
      attp  = att[(long)(eb+x)*NHEAD + m];
      amaxp = attmax[ccs[x]*NHEAD + m];
    }
    // ---- GEMV: aT = t @ Wrs[:,4j..4j+3] for 4 edges ----
    const float4* tp0 = (const float4*)(T + (long)(eb+0)*LAT);
    const float4* tp1 = (const float4*)(T + (long)(eb+1)*LAT);
    const float4* tp2 = (const float4*)(T + (long)(eb+2)*LAT);
    const float4* tp3 = (const float4*)(T + (long)(eb+3)*LAT);
    float4 aT[4];
    #pragma unroll
    for (int x = 0; x < 4; x++) aT[x] = make_float4(0.f,0.f,0.f,0.f);
    if (j < 54){
      #pragma unroll 2
      for (int kk = 0; kk < 16; kk++){
        float4 tv[4] = {tp0[kk], tp1[kk], tp2[kk], tp3[kk]};
        #pragma unroll
        for (int i = 0; i < 4; i++){
          const float4 r4 = *(const float4*)(srs + (kk*4+i)*216 + j*4);
          #pragma unroll
          for (int x = 0; x < 4; x++){
            float tx = f4g(tv[x], i);
            aT[x].x += tx*r4.x; aT[x].y += tx*r4.y; aT[x].z += tx*r4.z; aT[x].w += tx*r4.w;
          }
        }
      }
      #pragma unroll
      for (int x = 0; x < 4; x++){
        float4 ev4;
        ev4.x = aT[x].x * hw4[x].x;
        ev4.y = aT[x].y * hw4[x].y;
        ev4.z = aT[x].z * hw4[x].z;
        ev4.w = aT[x].w * hw4[x].w;
        *(float4*)&senv[lw][x][wpos] = ev4;
      }
    }
    if (j < 32){
      int x = j >> 3, m = j & 7;
      float ev = __expf(attp - amaxp);
      sev[lw][j] = ev;
      atomicAdd(&asum[ccs[x]*NHEAD + m], ev);
    }
    // hacc from senv cols 0..63 (positions unchanged by remap; same-wave DS in-order)
    #pragma unroll
    for (int x = 0; x < 4; x++){
      atomicAdd(&hacc[ccs[x]*LAT + j], senv[lw][x][j]);
    }
    // scatter: (d_sph + d_eq) * exp
    #pragma unroll
    for (int x = 0; x < 4; x++){
      const int cc = ccs[x];
      {
        int k3 = irrep_of(d0);
        float ds = sp0[x] * senv[lw][x][k3*8 + m0];
        float dq = 0.f;
        #pragma unroll
        for (int i = 0; i < 8; i++) dq += sxn[lw][x][i*9 + d0] * senv[lw][x][24 + k3*72 + i*8 + m0];
        float val = (ds + dq*RS8) * sev[lw][x*8 + m0];
        atomicAdd(&Xacc[cc*72 + j], val);
      }
      if (j < 8){
        int k3 = irrep_of(d1);
        float ds = sp1[x] * senv[lw][x][k3*8 + m1];
        float dq = 0.f;
        #pragma unroll
        for (int i = 0; i < 8; i++) dq += sxn[lw][x][i*9 + d1] * senv[lw][x][24 + k3*72 + i*8 + m1];
        float val = (ds + dq*RS8) * sev[lw][x*8 + m1];
        atomicAdd(&Xacc[cc*72 + 64 + j], val);
      }
    }
  }
}

// K8: h = LN(h+hacc); X = so3_norm(X + Xacc/(attsum+1e-12)); reset accumulators
__global__ void k_node_upd(float* __restrict__ hacc, float* __restrict__ attsum,
                           float* __restrict__ Xacc, float* __restrict__ amax,
                           const float* __restrict__ lg, const float* __restrict__ lb,
                           float* __restrict__ h, float* __restrict__ X){
  int n = blockIdx.x*(blockDim.x >> 6) + (threadIdx.x >> 6);
  int j = threadIdx.x & 63;
  if (n >= N_NODES) return;
  float hv = h[n*LAT + j] + hacc[n*LAT + j];
  float mu = wave_sum(hv) * (1.f/64.f);
  float va = wave_sum(hv*hv) * (1.f/64.f) - mu*mu;
  h[n*LAT + j] = (hv - mu) * rsqrtf(va + 1e-5f) * lg[j] + lb[j];

  float x0, x1 = 0.f;
  float s0 = 0.f, s1 = 0.f, s2 = 0.f;
  { int m = j/9, d = j - m*9;
    x0 = X[n*72 + j] + Xacc[n*72 + j] / (attsum[n*NHEAD + m] + 1e-12f);
    int k3 = irrep_of(d);
    if (k3 == 0) s0 = x0*x0; else if (k3 == 1) s1 = x0*x0; else s2 = x0*x0; }
  if (j < 8){ int tt = 64 + j; int m = tt/9, d = tt - m*9;
    x1 = X[n*72 + tt] + Xacc[n*72 + tt] / (attsum[n*NHEAD + m] + 1e-12f);
    int k3 = irrep_of(d);
    if (k3 == 0) s0 += x1*x1; else if (k3 == 1) s1 += x1*x1; else s2 += x1*x1; }
  s0 = wave_sum(s0); s1 = wave_sum(s1); s2 = wave_sum(s2);
  float sa = rsqrtf(s0*0.125f + 1e-5f), sb = rsqrtf(s1*0.125f + 1e-5f), sc = rsqrtf(s2*0.125f + 1e-5f);
  { int d = j % 9; int k3 = irrep_of(d);
    X[n*72 + j] = x0 * (k3==0 ? sa : (k3==1 ? sb : sc)); }
  if (j < 8){ int d = (64 + j) % 9; int k3 = irrep_of(d);
    X[n*72 + 64 + j] = x1 * (k3==0 ? sa : (k3==1 ? sb : sc)); }
  // reset accumulators for next layer
  Xacc[n*72 + j] = 0.f;
  if (j < 8) Xacc[n*72 + 64 + j] = 0.f;
  hacc[n*LAT + j] = 0.f;
  if (j < 8){ attsum[n*NHEAD + j] = 0.f; amax[n*NHEAD + j] = __uint_as_float(0xff800000u); }
}

// K9: w = h@W_hemb/8 -> (3,8,64); Xo = eq_linear(X,w); node_out
__global__ void k_node_out(const float* __restrict__ h, const float* __restrict__ X,
                           const float* __restrict__ Whemb,
                           float* __restrict__ out){
  __shared__ float sx[4][72];
  int n = blockIdx.x*(blockDim.x >> 6) + (threadIdx.x >> 6);
  int j = threadIdx.x & 63;
  int lw = threadIdx.x >> 6;
  if (n >= N_NODES) return;
  float hv = h[n*LAT + j];
  float wv[24];
  #pragma unroll
  for (int i = 0; i < 24; i++) wv[i] = 0.f;
  #pragma unroll 4
  for (int c = 0; c < LAT; c++){
    float hc = __shfl(hv, c);
    #pragma unroll
    for (int ki = 0; ki < 24; ki++)
      wv[ki] += hc * Whemb[c*1536 + ki*64 + j];
  }
  sx[lw][j] = X[n*72 + j];
  if (j < 8) sx[lw][64 + j] = X[n*72 + 64 + j];
  #pragma unroll
  for (int d = 0; d < 9; d++){
    int k3 = irrep_of(d);
    float acc = 0.f;
    #pragma unroll
    for (int i = 0; i < 8; i++) acc += sx[lw][i*9 + d] * wv[k3*8 + i];
    acc *= 0.125f * RS8;
    int pos;
    if (d == 0)      pos = n*576 + j;
    else if (d < 4)  pos = n*576 + 64  + j*3 + (d - 1);
    else             pos = n*576 + 256 + j*5 + (d - 4);
    out[pos] = acc;
  }
}

// ---- workspace layout (floats) — total 26.56M floats = 106.2 MB ----
static const long O_T    = 0;          // 20.48M  (E*64)
static const long O_ATT  = 20480000;   // 2.56M   (E*8) ; prologue pn/pc/mn/P0 alias here
static const long O_H0   = 23040000;   // 640k
static const long O_H    = 23680000;   // 640k
static const long O_X    = 24320000;   // 720k
static const long O_XACC = 25040000;   // 720k
static const long O_HACC = 25760000;   // 640k
static const long O_AMAX = 26400000;   // 80k
static const long O_ASUM = 26480000;   // 80k

extern "C" void kernel_launch(void* const* d_in, const int* in_sizes, int n_in,
                              void* d_out, int out_size, void* d_ws, size_t ws_size,
                              hipStream_t stream) {
  const float* na    = (const float*)d_in[0];
  const float* phi   = (const float*)d_in[1];
  const float* sph   = (const float*)d_in[2];
  const float* Wn    = (const float*)d_in[4];
  const float* Wc    = (const float*)d_in[5];
  const float* Wcat  = (const float*)d_in[6];
  const float* We    = (const float*)d_in[7];
  const float* ln0g  = (const float*)d_in[8];
  const float* ln0b  = (const float*)d_in[9];
  const float* lneg  = (const float*)d_in[10];
  const float* lneb  = (const float*)d_in[11];
  const float* Wtcat = (const float*)d_in[12];
  const float* Wt0   = (const float*)d_in[13];
  const float* Wh0   = (const float*)d_in[14];
  const float* Wrs   = (const float*)d_in[15];
  const float* Whj   = (const float*)d_in[16];
  const float* lnlg  = (const float*)d_in[17];
  const float* lnlb  = (const float*)d_in[18];
  const float* Wq    = (const float*)d_in[19];
  const float* Wk    = (const float*)d_in[20];
  const float* Whemb = (const float*)d_in[21];
  const float* Wtij  = (const float*)d_in[22];
  const int* ec = (const int*)d_in[23];
  const int* en = (const int*)d_in[24];

  float* ws   = (float*)d_ws;
  float* T    = ws + O_T;
  float* att  = ws + O_ATT;
  float* h0   = ws + O_H0;
  float* h    = ws + O_H;
  float* X    = ws + O_X;
  float* Xacc = ws + O_XACC;
  float* hacc = ws + O_HACC;
  float* amax = ws + O_AMAX;
  float* asum = ws + O_ASUM;
  // prologue-only buffers alias the att region (dead before k_att runs)
  float* pn   = att;
  float* pc   = att + 640000;
  float* mn   = att + 1280000;
  float* P0   = att;               // 1.52M, written after pn/pc/mn are dead

  float* out      = (float*)d_out;
  float* edge_out = out + (long)N_NODES*576;
  // per-layer node precomputes scratch in node_out region (written only at end)
  float* Hk = out;                 // 1.28M
  float* Hw = out + 1280000;       // 2.16M

  hipMemsetAsync(mn,   0, 640000*sizeof(float), stream);
  hipMemsetAsync(Xacc, 0, 720000*sizeof(float), stream);

  k_node_proj<<<(N_NODES*64)/256, 256, 0, stream>>>(na, Wn, Wc, pn, pc);
  k_edge_msg<<<1024, 256, 0, stream>>>(phi, We, ec, en, pn, mn);
  k_node_h<<<N_NODES/4, 256, 0, stream>>>(pc, mn, Wcat, ln0g, ln0b, h0, h);
  k_pre0<<<256, 256, 0, stream>>>(h0, Wtcat, Wh0, P0);
  k_tij<<<1024, 256, 0, stream>>>(P0, phi, sph, Wtcat, lneg, lneb, Wtij, Wt0,
                                  ec, en, T, Xacc, edge_out);
  k_node_X0<<<N_NODES/4, 256, 0, stream>>>(Xacc, X, hacc, asum, amax);

  for (int l = 0; l < NL; l++){
    k_node_mm<128><<<512, 256, 0, stream>>>(h, Wk + l*64*128, 128, 1.f, Hk);
    k_node_mm<216><<<512, 256, 0, stream>>>(h, Whj + (long)l*64*GEN_W, GEN_W, 0.125f, Hw);
    k_att<<<1024, 256, 0, stream>>>(T, Hk, Wq + l*64*128, ec, en, att, amax);
    k_env<<<256, 1024, 0, stream>>>(T, Hw, X, Wrs + (long)l*64*GEN_W, sph,
                                    att, amax, ec, en, hacc, asum, Xacc);
    k_node_upd<<<N_NODES/4, 256, 0, stream>>>(hacc, asum, Xacc, amax,
                                              lnlg + l*64, lnlb + l*64, h, X);
  }

  k_node_out<<<N_NODES/4, 256, 0, stream>>>(h, X, Whemb, out);
}

// Round 7
// 1786.475 us; speedup vs baseline: 1.0430x; 1.0430x over previous
//
#include <hip/hip_runtime.h>
#include <hip/hip_bf16.h>

#define N_NODES 10000
#define N_EDGES 320000
#define D_NODE 32
#define D_RAD 8
#define D_SPH 9
#define LAT 64
#define NHEAD 8
#define NL 2
#define GEN_W 280
#define WN_ENV 24

#define RS136 0.08574929257125442f   // 136^-0.5
#define RS8   0.35355339059327373f   // 8^-0.5

static_assert(N_EDGES % 4 == 0, "edge quads");

__device__ __forceinline__ int irrep_of(int d){ return (d==0)?0:((d<4)?1:2); }

__device__ __forceinline__ float wave_sum(float v){
  #pragma unroll
  for (int off=32; off; off>>=1) v += __shfl_xor(v, off);
  return v;
}

__device__ __forceinline__ void atomicMaxF(float* addr, float v){
  if (v >= 0.f) atomicMax((int*)addr, __float_as_int(v));
  else          atomicMin((unsigned int*)addr, __float_as_uint(v));
}

__device__ __forceinline__ float f4g(const float4& v, int i){
  return (i==0)?v.x:((i==1)?v.y:((i==2)?v.z:v.w));
}

// K1: pn = na@W_node, pc = na@W_center; also zero mnode and Xacc (replaces memsets)
__global__ void k_node_proj(const float* __restrict__ na,
                            const float* __restrict__ Wn,
                            const float* __restrict__ Wc,
                            float* __restrict__ pn, float* __restrict__ pc,
                            float* __restrict__ mnode, float* __restrict__ Xacc){
  int idx = blockIdx.x*blockDim.x + threadIdx.x;
  int n = idx >> 6, j = idx & 63;
  if (n >= N_NODES) return;
  float an = 0.f, ac = 0.f;
  #pragma unroll
  for (int k = 0; k < D_NODE; k++){
    float a = na[n*D_NODE + k];
    an += a * Wn[k*LAT + j];
    ac += a * Wc[k*LAT + j];
  }
  pn[idx] = an; pc[idx] = ac;
  mnode[idx] = 0.f;
  Xacc[n*72 + j] = 0.f;
  if (j < 8) Xacc[n*72 + 64 + j] = 0.f;
}

// K2: pe = pn[nb] * (phi@W_edge); m_node = segsum(pe). E=4, We in LDS.
__global__ void __launch_bounds__(256,4) k_edge_msg(const float* __restrict__ phi,
                           const float* __restrict__ We,
                           const int* __restrict__ ec, const int* __restrict__ en,
                           const float* __restrict__ pn, float* __restrict__ mnode){
  __shared__ float swe[8*64];
  for (int i = threadIdx.x; i < 8*64; i += 256) swe[i] = We[i];
  __syncthreads();
  const int j = threadIdx.x & 63;
  int wid = blockIdx.x*4 + (threadIdx.x >> 6);
  int nw  = gridDim.x*4;
  for (int p = wid; p < N_EDGES/4; p += nw){
    const int eb = p*4;
    int4 cv = *(const int4*)(ec + eb);
    int4 nv = *(const int4*)(en + eb);
    int c0 = __builtin_amdgcn_readfirstlane(cv.x);
    int c1 = __builtin_amdgcn_readfirstlane(cv.y);
    int c2 = __builtin_amdgcn_readfirstlane(cv.z);
    int c3 = __builtin_amdgcn_readfirstlane(cv.w);
    int n0 = __builtin_amdgcn_readfirstlane(nv.x);
    int n1 = __builtin_amdgcn_readfirstlane(nv.y);
    int n2 = __builtin_amdgcn_readfirstlane(nv.z);
    int n3 = __builtin_amdgcn_readfirstlane(nv.w);
    const float4* ph = (const float4*)(phi + (long)eb*D_RAD);
    float d0=0.f, d1=0.f, d2=0.f, d3=0.f;
    #pragma unroll
    for (int kk = 0; kk < 2; kk++){
      float4 p0=ph[kk], p1=ph[2+kk], p2=ph[4+kk], p3=ph[6+kk];
      #pragma unroll
      for (int i = 0; i < 4; i++){
        float u = swe[(kk*4+i)*64 + j];
        d0+=f4g(p0,i)*u; d1+=f4g(p1,i)*u; d2+=f4g(p2,i)*u; d3+=f4g(p3,i)*u;
      }
    }
    atomicAdd(&mnode[(long)c0*LAT + j], pn[(long)n0*LAT + j] * d0);
    atomicAdd(&mnode[(long)c1*LAT + j], pn[(long)n1*LAT + j] * d1);
    atomicAdd(&mnode[(long)c2*LAT + j], pn[(long)n2*LAT + j] * d2);
    atomicAdd(&mnode[(long)c3*LAT + j], pn[(long)n3*LAT + j] * d3);
  }
}

// K3: h0 = h = LN([pc, m_node]@W_concat)
__global__ void k_node_h(const float* __restrict__ pc, const float* __restrict__ mnode,
                         const float* __restrict__ Wcat,
                         const float* __restrict__ g, const float* __restrict__ b,
                         float* __restrict__ h0, float* __restrict__ h){
  int n = blockIdx.x*(blockDim.x >> 6) + (threadIdx.x >> 6);
  int j = threadIdx.x & 63;
  if (n >= N_NODES) return;
  float acc = 0.f;
  for (int k = 0; k < LAT; k++) acc += pc[n*LAT + k] * Wcat[k*LAT + j];
  for (int k = 0; k < LAT; k++) acc += mnode[n*LAT + k] * Wcat[(LAT + k)*LAT + j];
  float mu = wave_sum(acc) * (1.f/64.f);
  float va = wave_sum(acc*acc) * (1.f/64.f) - mu*mu;
  float v = (acc - mu) * rsqrtf(va + 1e-5f) * g[j] + b[j];
  h0[n*LAT + j] = v; h[n*LAT + j] = v;
}

// K3b: P0[n] = [ h0@Wtcat[0:64]*RS136 | h0@Wtcat[64:128]*RS136 | h0@Wh0*0.125 ]
__global__ void __launch_bounds__(256) k_pre0(const float* __restrict__ h0,
                       const float* __restrict__ Wtcat, const float* __restrict__ Wh0,
                       float* __restrict__ P0){
  __shared__ float sw[64*152];
  for (int i = threadIdx.x; i < 64*152; i += 256){
    int k = i / 152, c = i - k*152;
    float v;
    if (c < 64)       v = Wtcat[k*64 + c] * RS136;
    else if (c < 128) v = Wtcat[(64 + k)*64 + (c - 64)] * RS136;
    else              v = Wh0[k*24 + (c - 128)] * 0.125f;
    sw[i] = v;
  }
  __syncthreads();
  const int j = threadIdx.x & 63;
  int wid = blockIdx.x*4 + (threadIdx.x >> 6);
  int nw = gridDim.x*4;
  for (int n = wid; n < N_NODES; n += nw){
    const float4* xp = (const float4*)(h0 + (long)n*LAT);
    float a0=0.f, a1=0.f, a2=0.f;
    #pragma unroll 2
    for (int kk = 0; kk < 16; kk++){
      float4 xv = xp[kk];
      #pragma unroll
      for (int i = 0; i < 4; i++){
        float xi = f4g(xv, i);
        const float* w = sw + (kk*4+i)*152;
        a0 += xi * w[j];
        a1 += xi * w[64 + j];
        if (j < 24) a2 += xi * w[128 + j];
      }
    }
    P0[(long)n*152 + j] = a0;
    P0[(long)n*152 + 64 + j] = a1;
    if (j < 24) P0[(long)n*152 + 128 + j] = a2;
  }
}

// generic per-node GEMM: out[n][c] = scale * sum_k in[n][k]*W[k*ldw+c], c<C
template<int C>
__global__ void __launch_bounds__(256) k_node_mm(const float* __restrict__ in,
    const float* __restrict__ W, int ldw, float scale, float* __restrict__ out){
  __shared__ float sw[64*C];
  for (int i = threadIdx.x; i < 64*C; i += 256){
    int k = i / C, c = i - k*C;
    sw[i] = W[k*ldw + c] * scale;
  }
  __syncthreads();
  const int j = threadIdx.x & 63;
  constexpr int G = (C + 63)/64;
  int wid = blockIdx.x*4 + (threadIdx.x >> 6);
  int nw = gridDim.x*4;
  for (int n = wid; n < N_NODES; n += nw){
    const float4* xp = (const float4*)(in + (long)n*LAT);
    float acc[G];
    #pragma unroll
    for (int g = 0; g < G; g++) acc[g] = 0.f;
    #pragma unroll 2
    for (int kk = 0; kk < 16; kk++){
      float4 xv = xp[kk];
      #pragma unroll
      for (int i = 0; i < 4; i++){
        float xi = f4g(xv, i);
        int k = kk*4 + i;
        #pragma unroll
        for (int g = 0; g < G; g++){
          int c = g*64 + j;
          if (c < C) acc[g] += xi * sw[k*C + c];
        }
      }
    }
    #pragma unroll
    for (int g = 0; g < G; g++){
      int c = g*64 + j;
      if (c < C) out[(long)n*C + c] = acc[g];
    }
  }
}

// K4: fused tij. Phase1: t = LN(tA[c]+tB[nb]+phi@W3); phase2: edge_out=t@Wtij/8,
// w0 = (t@Wt0)*hh0[nb]*0.125 -> Xacc. k-packed float4 LDS weights (b128 reads).
// LDS 28KB -> 5 blk/CU.
__global__ void __launch_bounds__(256,5) k_tij(
    const float* __restrict__ P0, const float* __restrict__ phi,
    const float* __restrict__ sph,
    const float* __restrict__ Wtcat,
    const float* __restrict__ lg, const float* __restrict__ lb,
    const float* __restrict__ Wtij, const float* __restrict__ Wt0,
    const int* __restrict__ ec, const int* __restrict__ en,
    float* __restrict__ T, float* __restrict__ Xacc,
    float* __restrict__ edge_out){
  __shared__ float4 sW34[2*64];
  __shared__ float4 swij4[16*64];
  __shared__ float4 sw04[16*24];
  __shared__ float tst[4][4][64];
  for (int i = threadIdx.x; i < 2*64; i += 256){
    int kk = i >> 6, j2 = i & 63;
    sW34[i] = make_float4(Wtcat[(128+4*kk+0)*64 + j2]*RS136,
                          Wtcat[(128+4*kk+1)*64 + j2]*RS136,
                          Wtcat[(128+4*kk+2)*64 + j2]*RS136,
                          Wtcat[(128+4*kk+3)*64 + j2]*RS136);
  }
  for (int i = threadIdx.x; i < 16*64; i += 256){
    int kk = i >> 6, j2 = i & 63;
    swij4[i] = make_float4(Wtij[(4*kk+0)*64 + j2], Wtij[(4*kk+1)*64 + j2],
                           Wtij[(4*kk+2)*64 + j2], Wtij[(4*kk+3)*64 + j2]);
  }
  for (int i = threadIdx.x; i < 16*24; i += 256){
    int kk = i / 24, c = i - kk*24;
    sw04[i] = make_float4(Wt0[(4*kk+0)*24 + c], Wt0[(4*kk+1)*24 + c],
                          Wt0[(4*kk+2)*24 + c], Wt0[(4*kk+3)*24 + c]);
  }
  __syncthreads();
  const int j = threadIdx.x & 63, lw = threadIdx.x >> 6;
  const float gj = lg[j], bj = lb[j];
  const int jc = (j < 24) ? j : 0;
  int wid = blockIdx.x*4 + lw;
  int nw  = gridDim.x*4;
  for (int p = wid; p < N_EDGES/4; p += nw){
    const int eb = p*4;
    int4 cv = *(const int4*)(ec + eb);
    int4 nv = *(const int4*)(en + eb);
    int ccs[4], nns[4];
    ccs[0] = __builtin_amdgcn_readfirstlane(cv.x);
    ccs[1] = __builtin_amdgcn_readfirstlane(cv.y);
    ccs[2] = __builtin_amdgcn_readfirstlane(cv.z);
    ccs[3] = __builtin_amdgcn_readfirstlane(cv.w);
    nns[0] = __builtin_amdgcn_readfirstlane(nv.x);
    nns[1] = __builtin_amdgcn_readfirstlane(nv.y);
    nns[2] = __builtin_amdgcn_readfirstlane(nv.z);
    nns[3] = __builtin_amdgcn_readfirstlane(nv.w);
    // phase 1: gather + phi GEMV + LN
    float a[4], hh[4];
    #pragma unroll
    for (int x = 0; x < 4; x++){
      a[x]  = P0[(long)ccs[x]*152 + j] + P0[(long)nns[x]*152 + 64 + j];
      hh[x] = P0[(long)nns[x]*152 + 128 + jc];
    }
    const float4* ph = (const float4*)(phi + (long)eb*D_RAD);
    #pragma unroll
    for (int kk = 0; kk < 2; kk++){
      float4 p0=ph[kk], p1=ph[2+kk], p2=ph[4+kk], p3=ph[6+kk];
      float4 u4 = sW34[kk*64 + j];
      #pragma unroll
      for (int i = 0; i < 4; i++){
        float u = f4g(u4, i);
        a[0]+=f4g(p0,i)*u; a[1]+=f4g(p1,i)*u; a[2]+=f4g(p2,i)*u; a[3]+=f4g(p3,i)*u;
      }
    }
    #pragma unroll
    for (int x = 0; x < 4; x++){
      float acc = a[x];
      float mu = wave_sum(acc) * (1.f/64.f);
      float va = wave_sum(acc*acc) * (1.f/64.f) - mu*mu;
      float t = (acc - mu) * rsqrtf(va + 1e-5f) * gj + bj;
      T[(long)(eb+x)*LAT + j] = t;
      tst[lw][x][j] = t;
    }
    // phase 2 (tst same-wave DS: in-order, no fence needed)
    float eo[4]={0,0,0,0}, av[4]={0,0,0,0};
    #pragma unroll 2
    for (int kk = 0; kk < 16; kk++){
      float4 tv0 = *(const float4*)&tst[lw][0][kk*4];
      float4 tv1 = *(const float4*)&tst[lw][1][kk*4];
      float4 tv2 = *(const float4*)&tst[lw][2][kk*4];
      float4 tv3 = *(const float4*)&tst[lw][3][kk*4];
      float4 u4 = swij4[kk*64 + j];
      float4 w4 = sw04[kk*24 + jc];
      #pragma unroll
      for (int i = 0; i < 4; i++){
        float u = f4g(u4, i), w = f4g(w4, i);
        eo[0]+=f4g(tv0,i)*u; av[0]+=f4g(tv0,i)*w;
        eo[1]+=f4g(tv1,i)*u; av[1]+=f4g(tv1,i)*w;
        eo[2]+=f4g(tv2,i)*u; av[2]+=f4g(tv2,i)*w;
        eo[3]+=f4g(tv3,i)*u; av[3]+=f4g(tv3,i)*w;
      }
    }
    float w0s[4];
    #pragma unroll
    for (int x = 0; x < 4; x++){
      edge_out[(long)(eb+x)*LAT + j] = eo[x] * 0.125f;
      w0s[x] = av[x] * hh[x] * 0.125f;
    }
    #pragma unroll
    for (int x = 0; x < 4; x++){
      #pragma unroll
      for (int rep = 0; rep < 2; rep++){
        int tt = j + rep*64;
        int m = tt/9, d = tt - (tt/9)*9;
        int wi = (tt < 72) ? (irrep_of(d)*NHEAD + m) : 0;
        float wv = __shfl(w0s[x], wi);
        if (tt < 72){
          atomicAdd(&Xacc[ccs[x]*72 + tt], sph[(long)(eb+x)*D_SPH + d] * wv);
        }
      }
    }
  }
}

// K5: X = so3_norm(Xacc); also zero/init per-layer accumulators (hacc/asum/amax/Xacc)
__global__ void k_node_X0(float* __restrict__ Xacc, float* __restrict__ X,
                          float* __restrict__ hacc, float* __restrict__ asum,
                          float* __restrict__ amax){
  int n = blockIdx.x*(blockDim.x >> 6) + (threadIdx.x >> 6);
  int j = threadIdx.x & 63;
  if (n >= N_NODES) return;
  float x0 = Xacc[n*72 + j];
  float x1 = (j < 8) ? Xacc[n*72 + 64 + j] : 0.f;
  float s0 = 0.f, s1 = 0.f, s2 = 0.f;
  { int d = j % 9; int k3 = irrep_of(d);
    if (k3 == 0) s0 = x0*x0; else if (k3 == 1) s1 = x0*x0; else s2 = x0*x0; }
  if (j < 8){ int d = (64 + j) % 9; int k3 = irrep_of(d);
    if (k3 == 0) s0 += x1*x1; else if (k3 == 1) s1 += x1*x1; else s2 += x1*x1; }
  s0 = wave_sum(s0); s1 = wave_sum(s1); s2 = wave_sum(s2);
  float sa = rsqrtf(s0*0.125f + 1e-5f), sb = rsqrtf(s1*0.125f + 1e-5f), sc = rsqrtf(s2*0.125f + 1e-5f);
  { int d = j % 9; int k3 = irrep_of(d);
    X[n*72 + j] = x0 * (k3==0 ? sa : (k3==1 ? sb : sc)); }
  if (j < 8){ int d = (64 + j) % 9; int k3 = irrep_of(d);
    X[n*72 + 64 + j] = x1 * (k3==0 ? sa : (k3==1 ? sb : sc)); }
  // reset accumulators for layer 0
  Xacc[n*72 + j] = 0.f;
  if (j < 8) Xacc[n*72 + 64 + j] = 0.f;
  hacc[n*LAT + j] = 0.f;
  if (j < 8){ asum[n*NHEAD + j] = 0.f; amax[n*NHEAD + j] = __uint_as_float(0xff800000u); }
}

// K6: attention logits + running max. Q = t@Wq; K gathered from Hk.
// k-packed float4 weights -> 2 b128/kk. LDS 32KB -> 4 blk/CU.
__global__ void __launch_bounds__(256,4) k_att(const float* __restrict__ T, const float* __restrict__ Hk,
                     const float* __restrict__ Wq,
                     const int* __restrict__ ec, const int* __restrict__ en,
                     float* __restrict__ att, float* __restrict__ attmax){
  __shared__ float4 sqa[16*64], sqb[16*64];
  for (int i = threadIdx.x; i < 16*64; i += 256){
    int kk = i >> 6, j2 = i & 63;
    sqa[i] = make_float4(Wq[(4*kk+0)*128 + j2], Wq[(4*kk+1)*128 + j2],
                         Wq[(4*kk+2)*128 + j2], Wq[(4*kk+3)*128 + j2]);
    sqb[i] = make_float4(Wq[(4*kk+0)*128 + 64 + j2], Wq[(4*kk+1)*128 + 64 + j2],
                         Wq[(4*kk+2)*128 + 64 + j2], Wq[(4*kk+3)*128 + 64 + j2]);
  }
  __syncthreads();
  const int j = threadIdx.x & 63;
  int wid = blockIdx.x*4 + (threadIdx.x >> 6);
  int nw  = gridDim.x*4;
  for (int p = wid; p < N_EDGES/4; p += nw){
    const int eb = p*4;
    int4 cv = *(const int4*)(ec + eb);
    int4 nv = *(const int4*)(en + eb);
    int ccs[4], nns[4];
    ccs[0] = __builtin_amdgcn_readfirstlane(cv.x);
    ccs[1] = __builtin_amdgcn_readfirstlane(cv.y);
    ccs[2] = __builtin_amdgcn_readfirstlane(cv.z);
    ccs[3] = __builtin_amdgcn_readfirstlane(cv.w);
    nns[0] = __builtin_amdgcn_readfirstlane(nv.x);
    nns[1] = __builtin_amdgcn_readfirstlane(nv.y);
    nns[2] = __builtin_amdgcn_readfirstlane(nv.z);
    nns[3] = __builtin_amdgcn_readfirstlane(nv.w);
    float ha[4], hb[4];
    #pragma unroll
    for (int x = 0; x < 4; x++){
      ha[x] = Hk[(long)nns[x]*128 + j];
      hb[x] = Hk[(long)nns[x]*128 + 64 + j];
    }
    const float4* tp0 = (const float4*)(T + (long)(eb+0)*LAT);
    const float4* tp1 = (const float4*)(T + (long)(eb+1)*LAT);
    const float4* tp2 = (const float4*)(T + (long)(eb+2)*LAT);
    const float4* tp3 = (const float4*)(T + (long)(eb+3)*LAT);
    float qa[4]={0,0,0,0}, qb[4]={0,0,0,0};
    #pragma unroll 2
    for (int kk = 0; kk < 16; kk++){
      float4 tv[4] = {tp0[kk], tp1[kk], tp2[kk], tp3[kk]};
      float4 wa = sqa[kk*64 + j];
      float4 wb = sqb[kk*64 + j];
      #pragma unroll
      for (int i = 0; i < 4; i++){
        float q0 = f4g(wa, i), q1 = f4g(wb, i);
        #pragma unroll
        for (int x = 0; x < 4; x++){
          float tx = f4g(tv[x], i);
          qa[x] += tx*q0; qb[x] += tx*q1;
        }
      }
    }
    float pa[4], pb[4];
    #pragma unroll
    for (int x = 0; x < 4; x++){ pa[x] = qa[x]*ha[x]; pb[x] = qb[x]*hb[x]; }
    #pragma unroll
    for (int off = 8; off; off >>= 1){
      #pragma unroll
      for (int x = 0; x < 4; x++){
        pa[x] += __shfl_xor(pa[x], off);
        pb[x] += __shfl_xor(pb[x], off);
      }
    }
    if ((j & 15) == 0){
      int m = j >> 4;
      #pragma unroll
      for (int x = 0; x < 4; x++){
        float A = 4.f*pa[x], B = 4.f*pb[x];
        att[(long)(eb+x)*NHEAD + m] = A;
        att[(long)(eb+x)*NHEAD + 4 + m] = B;
        atomicMaxF(&attmax[ccs[x]*NHEAD + m], A);
        atomicMaxF(&attmax[ccs[x]*NHEAD + 4 + m], B);
      }
    }
  }
}

// K7: env = (t@Wrs[:216]) * Hw[nb]; hacc/asum/Xacc scatter in one pass.
// 1024 thr (16 waves) / 1 blk/CU. Round-5 load ordering (no prefetch hoisting —
// it regressed: compiler pins VGPR=64 and defeats it). senv stored with
// k3-stride 72: dq-read windows at banks {24..31},{0..7},{8..15} (was 3-way
// overlapped at stride 64 — the 5.1M-conflict source). LDS 139264 B.
__global__ void __launch_bounds__(1024,4) k_env(
    const float* __restrict__ T, const float* __restrict__ Hw,
    const float* __restrict__ X,
    const float* __restrict__ Wrs,
    const float* __restrict__ sph,
    const float* __restrict__ att, const float* __restrict__ attmax,
    const int* __restrict__ ec, const int* __restrict__ en,
    float* __restrict__ hacc, float* __restrict__ asum,
    float* __restrict__ Xacc){
  __shared__ float srs[64*216];
  __shared__ float senv[16][4][240];
  __shared__ float sxn[16][4][80];
  __shared__ float sev[16][32];
  for (int i = threadIdx.x; i < 64*216; i += 1024){
    int k = i / 216, c = i - k*216;
    srs[i] = Wrs[k*GEN_W + c];
  }
  __syncthreads();
  const int j = threadIdx.x & 63, lw = threadIdx.x >> 6;
  int wpos = 0;
  if (j < 54){
    int c0 = 4*j;
    wpos = (c0 < 24) ? c0 : 24 + ((c0-24) >> 6)*72 + ((c0-24) & 63);
  }
  const int d0 = j - (j/9)*9, m0 = j/9;   // rep0: tt=j
  const int d1 = 1 + j, m1 = 7;            // rep1: tt=64+j (j<8)
  int wid = blockIdx.x*16 + lw;
  int nw  = gridDim.x*16;
  for (int p = wid; p < N_EDGES/4; p += nw){
    const int eb = p*4;
    int4 cv = *(const int4*)(ec + eb);
    int4 nv = *(const int4*)(en + eb);
    int ccs[4], nns[4];
    ccs[0] = __builtin_amdgcn_readfirstlane(cv.x);
    ccs[1] = __builtin_amdgcn_readfirstlane(cv.y);
    ccs[2] = __builtin_amdgcn_readfirstlane(cv.z);
    ccs[3] = __builtin_amdgcn_readfirstlane(cv.w);
    nns[0] = __builtin_amdgcn_readfirstlane(nv.x);
    nns[1] = __builtin_amdgcn_readfirstlane(nv.y);
    nns[2] = __builtin_amdgcn_readfirstlane(nv.z);
    nns[3] = __builtin_amdgcn_readfirstlane(nv.w);
    // stage X rows (coalesced) for the d_eq gathers
    #pragma unroll
    for (int x = 0; x < 4; x++){
      const float* Xr = X + (long)nns[x]*72;
      sxn[lw][x][j] = Xr[j];
      if (j < 8) sxn[lw][x][64 + j] = Xr[64 + j];
    }
    const float4* tp0 = (const float4*)(T + (long)(eb+0)*LAT);
    const float4* tp1 = (const float4*)(T + (long)(eb+1)*LAT);
    const float4* tp2 = (const float4*)(T + (long)(eb+2)*LAT);
    const float4* tp3 = (const float4*)(T + (long)(eb+3)*LAT);
    float4 aT[4];
    #pragma unroll
    for (int x = 0; x < 4; x++) aT[x] = make_float4(0.f,0.f,0.f,0.f);
    if (j < 54){
      #pragma unroll 2
      for (int kk = 0; kk < 16; kk++){
        float4 tv[4] = {tp0[kk], tp1[kk], tp2[kk], tp3[kk]};
        #pragma unroll
        for (int i = 0; i < 4; i++){
          const float4 r4 = *(const float4*)(srs + (kk*4+i)*216 + j*4);
          #pragma unroll
          for (int x = 0; x < 4; x++){
            float tx = f4g(tv[x], i);
            aT[x].x += tx*r4.x; aT[x].y += tx*r4.y; aT[x].z += tx*r4.z; aT[x].w += tx*r4.w;
          }
        }
      }
      #pragma unroll
      for (int x = 0; x < 4; x++){
        const float4 hw4 = *(const float4*)(Hw + (long)nns[x]*216 + j*4);
        float4 ev4;
        ev4.x = aT[x].x * hw4.x;
        ev4.y = aT[x].y * hw4.y;
        ev4.z = aT[x].z * hw4.z;
        ev4.w = aT[x].w * hw4.w;
        *(float4*)&senv[lw][x][wpos] = ev4;
      }
    }
    if (j < 32){
      int x = j >> 3, m = j & 7;
      int cc = ccs[x];
      float ev = __expf(att[(long)(eb+x)*NHEAD + m] - attmax[cc*NHEAD + m]);
      sev[lw][j] = ev;
      atomicAdd(&asum[cc*NHEAD + m], ev);
    }
    // hacc from senv cols 0..63 (positions unchanged by remap; same-wave DS in-order)
    #pragma unroll
    for (int x = 0; x < 4; x++){
      atomicAdd(&hacc[ccs[x]*LAT + j], senv[lw][x][j]);
    }
    // scatter: (d_sph + d_eq) * exp
    #pragma unroll
    for (int x = 0; x < 4; x++){
      const long e = eb + x;
      const int cc = ccs[x];
      {
        int k3 = irrep_of(d0);
        float ds = sph[e*D_SPH + d0] * senv[lw][x][k3*8 + m0];
        float dq = 0.f;
        #pragma unroll
        for (int i = 0; i < 8; i++) dq += sxn[lw][x][i*9 + d0] * senv[lw][x][24 + k3*72 + i*8 + m0];
        float val = (ds + dq*RS8) * sev[lw][x*8 + m0];
        atomicAdd(&Xacc[cc*72 + j], val);
      }
      if (j < 8){
        int k3 = irrep_of(d1);
        float ds = sph[e*D_SPH + d1] * senv[lw][x][k3*8 + m1];
        float dq = 0.f;
        #pragma unroll
        for (int i = 0; i < 8; i++) dq += sxn[lw][x][i*9 + d1] * senv[lw][x][24 + k3*72 + i*8 + m1];
        float val = (ds + dq*RS8) * sev[lw][x*8 + m1];
        atomicAdd(&Xacc[cc*72 + 64 + j], val);
      }
    }
  }
}

// K8: h = LN(h+hacc); X = so3_norm(X + Xacc/(attsum+1e-12)); reset accumulators
__global__ void k_node_upd(float* __restrict__ hacc, float* __restrict__ attsum,
                           float* __restrict__ Xacc, float* __restrict__ amax,
                           const float* __restrict__ lg, const float* __restrict__ lb,
                           float* __restrict__ h, float* __restrict__ X){
  int n = blockIdx.x*(blockDim.x >> 6) + (threadIdx.x >> 6);
  int j = threadIdx.x & 63;
  if (n >= N_NODES) return;
  float hv = h[n*LAT + j] + hacc[n*LAT + j];
  float mu = wave_sum(hv) * (1.f/64.f);
  float va = wave_sum(hv*hv) * (1.f/64.f) - mu*mu;
  h[n*LAT + j] = (hv - mu) * rsqrtf(va + 1e-5f) * lg[j] + lb[j];

  float x0, x1 = 0.f;
  float s0 = 0.f, s1 = 0.f, s2 = 0.f;
  { int m = j/9, d = j - m*9;
    x0 = X[n*72 + j] + Xacc[n*72 + j] / (attsum[n*NHEAD + m] + 1e-12f);
    int k3 = irrep_of(d);
    if (k3 == 0) s0 = x0*x0; else if (k3 == 1) s1 = x0*x0; else s2 = x0*x0; }
  if (j < 8){ int tt = 64 + j; int m = tt/9, d = tt - m*9;
    x1 = X[n*72 + tt] + Xacc[n*72 + tt] / (attsum[n*NHEAD + m] + 1e-12f);
    int k3 = irrep_of(d);
    if (k3 == 0) s0 += x1*x1; else if (k3 == 1) s1 += x1*x1; else s2 += x1*x1; }
  s0 = wave_sum(s0); s1 = wave_sum(s1); s2 = wave_sum(s2);
  float sa = rsqrtf(s0*0.125f + 1e-5f), sb = rsqrtf(s1*0.125f + 1e-5f), sc = rsqrtf(s2*0.125f + 1e-5f);
  { int d = j % 9; int k3 = irrep_of(d);
    X[n*72 + j] = x0 * (k3==0 ? sa : (k3==1 ? sb : sc)); }
  if (j < 8){ int d = (64 + j) % 9; int k3 = irrep_of(d);
    X[n*72 + 64 + j] = x1 * (k3==0 ? sa : (k3==1 ? sb : sc)); }
  // reset accumulators for next layer
  Xacc[n*72 + j] = 0.f;
  if (j < 8) Xacc[n*72 + 64 + j] = 0.f;
  hacc[n*LAT + j] = 0.f;
  if (j < 8){ attsum[n*NHEAD + j] = 0.f; amax[n*NHEAD + j] = __uint_as_float(0xff800000u); }
}

// K9: w = h@W_hemb/8 -> (3,8,64); Xo = eq_linear(X,w); node_out
__global__ void k_node_out(const float* __restrict__ h, const float* __restrict__ X,
                           const float* __restrict__ Whemb,
                           float* __restrict__ out){
  __shared__ float sx[4][72];
  int n = blockIdx.x*(blockDim.x >> 6) + (threadIdx.x >> 6);
  int j = threadIdx.x & 63;
  int lw = threadIdx.x >> 6;
  if (n >= N_NODES) return;
  float hv = h[n*LAT + j];
  float wv[24];
  #pragma unroll
  for (int i = 0; i < 24; i++) wv[i] = 0.f;
  #pragma unroll 4
  for (int c = 0; c < LAT; c++){
    float hc = __shfl(hv, c);
    #pragma unroll
    for (int ki = 0; ki < 24; ki++)
      wv[ki] += hc * Whemb[c*1536 + ki*64 + j];
  }
  sx[lw][j] = X[n*72 + j];
  if (j < 8) sx[lw][64 + j] = X[n*72 + 64 + j];
  #pragma unroll
  for (int d = 0; d < 9; d++){
    int k3 = irrep_of(d);
    float acc = 0.f;
    #pragma unroll
    for (int i = 0; i < 8; i++) acc += sx[lw][i*9 + d] * wv[k3*8 + i];
    acc *= 0.125f * RS8;
    int pos;
    if (d == 0)      pos = n*576 + j;
    else if (d < 4)  pos = n*576 + 64  + j*3 + (d - 1);
    else             pos = n*576 + 256 + j*5 + (d - 4);
    out[pos] = acc;
  }
}

// ---- workspace layout (floats) — total 26.56M floats = 106.2 MB ----
static const long O_T    = 0;          // 20.48M  (E*64)
static const long O_ATT  = 20480000;   // 2.56M   (E*8) ; prologue pn/pc/mn/P0 alias here
static const long O_H0   = 23040000;   // 640k
static const long O_H    = 23680000;   // 640k
static const long O_X    = 24320000;   // 720k
static const long O_XACC = 25040000;   // 720k
static const long O_HACC = 25760000;   // 640k
static const long O_AMAX = 26400000;   // 80k
static const long O_ASUM = 26480000;   // 80k

extern "C" void kernel_launch(void* const* d_in, const int* in_sizes, int n_in,
                              void* d_out, int out_size, void* d_ws, size_t ws_size,
                              hipStream_t stream) {
  const float* na    = (const float*)d_in[0];
  const float* phi   = (const float*)d_in[1];
  const float* sph   = (const float*)d_in[2];
  const float* Wn    = (const float*)d_in[4];
  const float* Wc    = (const float*)d_in[5];
  const float* Wcat  = (const float*)d_in[6];
  const float* We    = (const float*)d_in[7];
  const float* ln0g  = (const float*)d_in[8];
  const float* ln0b  = (const float*)d_in[9];
  const float* lneg  = (const float*)d_in[10];
  const float* lneb  = (const float*)d_in[11];
  const float* Wtcat = (const float*)d_in[12];
  const float* Wt0   = (const float*)d_in[13];
  const float* Wh0   = (const float*)d_in[14];
  const float* Wrs   = (const float*)d_in[15];
  const float* Whj   = (const float*)d_in[16];
  const float* lnlg  = (const float*)d_in[17];
  const float* lnlb  = (const float*)d_in[18];
  const float* Wq    = (const float*)d_in[19];
  const float* Wk    = (const float*)d_in[20];
  const float* Whemb = (const float*)d_in[21];
  const float* Wtij  = (const float*)d_in[22];
  const int* ec = (const int*)d_in[23];
  const int* en = (const int*)d_in[24];

  float* ws   = (float*)d_ws;
  float* T    = ws + O_T;
  float* att  = ws + O_ATT;
  float* h0   = ws + O_H0;
  float* h    = ws + O_H;
  float* X    = ws + O_X;
  float* Xacc = ws + O_XACC;
  float* hacc = ws + O_HACC;
  float* amax = ws + O_AMAX;
  float* asum = ws + O_ASUM;
  // prologue-only buffers alias the att region (dead before k_att runs)
  float* pn   = att;
  float* pc   = att + 640000;
  float* mn   = att + 1280000;
  float* P0   = att;               // 1.52M, written after pn/pc/mn are dead

  float* out      = (float*)d_out;
  float* edge_out = out + (long)N_NODES*576;
  // per-layer node precomputes scratch in node_out region (written only at end)
  float* Hk = out;                 // 1.28M
  float* Hw = out + 1280000;       // 2.16M

  k_node_proj<<<(N_NODES*64)/256, 256, 0, stream>>>(na, Wn, Wc, pn, pc, mn, Xacc);
  k_edge_msg<<<1024, 256, 0, stream>>>(phi, We, ec, en, pn, mn);
  k_node_h<<<N_NODES/4, 256, 0, stream>>>(pc, mn, Wcat, ln0g, ln0b, h0, h);
  k_pre0<<<256, 256, 0, stream>>>(h0, Wtcat, Wh0, P0);
  k_tij<<<1024, 256, 0, stream>>>(P0, phi, sph, Wtcat, lneg, lneb, Wtij, Wt0,
                                  ec, en, T, Xacc, edge_out);
  k_node_X0<<<N_NODES/4, 256, 0, stream>>>(Xacc, X, hacc, asum, amax);

  for (int l = 0; l < NL; l++){
    k_node_mm<128><<<512, 256, 0, stream>>>(h, Wk + l*64*128, 128, 1.f, Hk);
    k_node_mm<216><<<512, 256, 0, stream>>>(h, Whj + (long)l*64*GEN_W, GEN_W, 0.125f, Hw);
    k_att<<<1024, 256, 0, stream>>>(T, Hk, Wq + l*64*128, ec, en, att, amax);
    k_env<<<256, 1024, 0, stream>>>(T, Hw, X, Wrs + (long)l*64*GEN_W, sph,
                                    att, amax, ec, en, hacc, asum, Xacc);
    k_node_upd<<<N_NODES/4, 256, 0, stream>>>(hacc, asum, Xacc, amax,
                                              lnlg + l*64, lnlb + l*64, h, X);
  }

  k_node_out<<<N_NODES/4, 256, 0, stream>>>(h, X, Whemb, out);
}

// Round 8
// 1527.944 us; speedup vs baseline: 1.2195x; 1.1692x over previous
//
#include <hip/hip_runtime.h>
#include <hip/hip_bf16.h>

#define N_NODES 10000
#define N_EDGES 320000
#define D_NODE 32
#define D_RAD 8
#define D_SPH 9
#define LAT 64
#define NHEAD 8
#define NL 2
#define GEN_W 280
#define WN_ENV 24

#define RS136 0.08574929257125442f   // 136^-0.5
#define RS8   0.35355339059327373f   // 8^-0.5

static_assert(N_EDGES % 4 == 0, "edge quads");

__device__ __forceinline__ int irrep_of(int d){ return (d==0)?0:((d<4)?1:2); }

__device__ __forceinline__ float wave_sum(float v){
  #pragma unroll
  for (int off=32; off; off>>=1) v += __shfl_xor(v, off);
  return v;
}

__device__ __forceinline__ void atomicMaxF(float* addr, float v){
  if (v >= 0.f) atomicMax((int*)addr, __float_as_int(v));
  else          atomicMin((unsigned int*)addr, __float_as_uint(v));
}

__device__ __forceinline__ float f4g(const float4& v, int i){
  return (i==0)?v.x:((i==1)?v.y:((i==2)?v.z:v.w));
}

// K1: pn = na@W_node, pc = na@W_center; also zero mnode and Xacc (replaces memsets)
__global__ void k_node_proj(const float* __restrict__ na,
                            const float* __restrict__ Wn,
                            const float* __restrict__ Wc,
                            float* __restrict__ pn, float* __restrict__ pc,
                            float* __restrict__ mnode, float* __restrict__ Xacc){
  int idx = blockIdx.x*blockDim.x + threadIdx.x;
  int n = idx >> 6, j = idx & 63;
  if (n >= N_NODES) return;
  float an = 0.f, ac = 0.f;
  #pragma unroll
  for (int k = 0; k < D_NODE; k++){
    float a = na[n*D_NODE + k];
    an += a * Wn[k*LAT + j];
    ac += a * Wc[k*LAT + j];
  }
  pn[idx] = an; pc[idx] = ac;
  mnode[idx] = 0.f;
  Xacc[n*72 + j] = 0.f;
  if (j < 8) Xacc[n*72 + 64 + j] = 0.f;
}

// K2: pe = pn[nb] * (phi@W_edge); m_node = segsum(pe). E=4, We in LDS.
__global__ void __launch_bounds__(256,4) k_edge_msg(const float* __restrict__ phi,
                           const float* __restrict__ We,
                           const int* __restrict__ ec, const int* __restrict__ en,
                           const float* __restrict__ pn, float* __restrict__ mnode){
  __shared__ float swe[8*64];
  for (int i = threadIdx.x; i < 8*64; i += 256) swe[i] = We[i];
  __syncthreads();
  const int j = threadIdx.x & 63;
  int wid = blockIdx.x*4 + (threadIdx.x >> 6);
  int nw  = gridDim.x*4;
  for (int p = wid; p < N_EDGES/4; p += nw){
    const int eb = p*4;
    int4 cv = *(const int4*)(ec + eb);
    int4 nv = *(const int4*)(en + eb);
    int c0 = __builtin_amdgcn_readfirstlane(cv.x);
    int c1 = __builtin_amdgcn_readfirstlane(cv.y);
    int c2 = __builtin_amdgcn_readfirstlane(cv.z);
    int c3 = __builtin_amdgcn_readfirstlane(cv.w);
    int n0 = __builtin_amdgcn_readfirstlane(nv.x);
    int n1 = __builtin_amdgcn_readfirstlane(nv.y);
    int n2 = __builtin_amdgcn_readfirstlane(nv.z);
    int n3 = __builtin_amdgcn_readfirstlane(nv.w);
    const float4* ph = (const float4*)(phi + (long)eb*D_RAD);
    float d0=0.f, d1=0.f, d2=0.f, d3=0.f;
    #pragma unroll
    for (int kk = 0; kk < 2; kk++){
      float4 p0=ph[kk], p1=ph[2+kk], p2=ph[4+kk], p3=ph[6+kk];
      #pragma unroll
      for (int i = 0; i < 4; i++){
        float u = swe[(kk*4+i)*64 + j];
        d0+=f4g(p0,i)*u; d1+=f4g(p1,i)*u; d2+=f4g(p2,i)*u; d3+=f4g(p3,i)*u;
      }
    }
    atomicAdd(&mnode[(long)c0*LAT + j], pn[(long)n0*LAT + j] * d0);
    atomicAdd(&mnode[(long)c1*LAT + j], pn[(long)n1*LAT + j] * d1);
    atomicAdd(&mnode[(long)c2*LAT + j], pn[(long)n2*LAT + j] * d2);
    atomicAdd(&mnode[(long)c3*LAT + j], pn[(long)n3*LAT + j] * d3);
  }
}

// K3: h0 = h = LN([pc, m_node]@W_concat)
__global__ void k_node_h(const float* __restrict__ pc, const float* __restrict__ mnode,
                         const float* __restrict__ Wcat,
                         const float* __restrict__ g, const float* __restrict__ b,
                         float* __restrict__ h0, float* __restrict__ h){
  int n = blockIdx.x*(blockDim.x >> 6) + (threadIdx.x >> 6);
  int j = threadIdx.x & 63;
  if (n >= N_NODES) return;
  float acc = 0.f;
  for (int k = 0; k < LAT; k++) acc += pc[n*LAT + k] * Wcat[k*LAT + j];
  for (int k = 0; k < LAT; k++) acc += mnode[n*LAT + k] * Wcat[(LAT + k)*LAT + j];
  float mu = wave_sum(acc) * (1.f/64.f);
  float va = wave_sum(acc*acc) * (1.f/64.f) - mu*mu;
  float v = (acc - mu) * rsqrtf(va + 1e-5f) * g[j] + b[j];
  h0[n*LAT + j] = v; h[n*LAT + j] = v;
}

// K3b: P0[n] = [ h0@Wtcat[0:64]*RS136 | h0@Wtcat[64:128]*RS136 | h0@Wh0*0.125 ]
__global__ void __launch_bounds__(256) k_pre0(const float* __restrict__ h0,
                       const float* __restrict__ Wtcat, const float* __restrict__ Wh0,
                       float* __restrict__ P0){
  __shared__ float sw[64*152];
  for (int i = threadIdx.x; i < 64*152; i += 256){
    int k = i / 152, c = i - k*152;
    float v;
    if (c < 64)       v = Wtcat[k*64 + c] * RS136;
    else if (c < 128) v = Wtcat[(64 + k)*64 + (c - 64)] * RS136;
    else              v = Wh0[k*24 + (c - 128)] * 0.125f;
    sw[i] = v;
  }
  __syncthreads();
  const int j = threadIdx.x & 63;
  int wid = blockIdx.x*4 + (threadIdx.x >> 6);
  int nw = gridDim.x*4;
  for (int n = wid; n < N_NODES; n += nw){
    const float4* xp = (const float4*)(h0 + (long)n*LAT);
    float a0=0.f, a1=0.f, a2=0.f;
    #pragma unroll 2
    for (int kk = 0; kk < 16; kk++){
      float4 xv = xp[kk];
      #pragma unroll
      for (int i = 0; i < 4; i++){
        float xi = f4g(xv, i);
        const float* w = sw + (kk*4+i)*152;
        a0 += xi * w[j];
        a1 += xi * w[64 + j];
        if (j < 24) a2 += xi * w[128 + j];
      }
    }
    P0[(long)n*152 + j] = a0;
    P0[(long)n*152 + 64 + j] = a1;
    if (j < 24) P0[(long)n*152 + 128 + j] = a2;
  }
}

// generic per-node GEMM: out[n][c] = scale * sum_k in[n][k]*W[k*ldw+c], c<C
template<int C>
__global__ void __launch_bounds__(256) k_node_mm(const float* __restrict__ in,
    const float* __restrict__ W, int ldw, float scale, float* __restrict__ out){
  __shared__ float sw[64*C];
  for (int i = threadIdx.x; i < 64*C; i += 256){
    int k = i / C, c = i - k*C;
    sw[i] = W[k*ldw + c] * scale;
  }
  __syncthreads();
  const int j = threadIdx.x & 63;
  constexpr int G = (C + 63)/64;
  int wid = blockIdx.x*4 + (threadIdx.x >> 6);
  int nw = gridDim.x*4;
  for (int n = wid; n < N_NODES; n += nw){
    const float4* xp = (const float4*)(in + (long)n*LAT);
    float acc[G];
    #pragma unroll
    for (int g = 0; g < G; g++) acc[g] = 0.f;
    #pragma unroll 2
    for (int kk = 0; kk < 16; kk++){
      float4 xv = xp[kk];
      #pragma unroll
      for (int i = 0; i < 4; i++){
        float xi = f4g(xv, i);
        int k = kk*4 + i;
        #pragma unroll
        for (int g = 0; g < G; g++){
          int c = g*64 + j;
          if (c < C) acc[g] += xi * sw[k*C + c];
        }
      }
    }
    #pragma unroll
    for (int g = 0; g < G; g++){
      int c = g*64 + j;
      if (c < C) out[(long)n*C + c] = acc[g];
    }
  }
}

// K4: fused tij. Phase1: t = LN(tA[c]+tB[nb]+phi@W3); phase2: edge_out=t@Wtij/8,
// w0 = (t@Wt0)*hh0[nb]*0.125 -> Xacc. k-packed float4 LDS weights (b128 reads).
// LDS 28KB -> 5 blk/CU.
__global__ void __launch_bounds__(256,5) k_tij(
    const float* __restrict__ P0, const float* __restrict__ phi,
    const float* __restrict__ sph,
    const float* __restrict__ Wtcat,
    const float* __restrict__ lg, const float* __restrict__ lb,
    const float* __restrict__ Wtij, const float* __restrict__ Wt0,
    const int* __restrict__ ec, const int* __restrict__ en,
    float* __restrict__ T, float* __restrict__ Xacc,
    float* __restrict__ edge_out){
  __shared__ float4 sW34[2*64];
  __shared__ float4 swij4[16*64];
  __shared__ float4 sw04[16*24];
  __shared__ float tst[4][4][64];
  for (int i = threadIdx.x; i < 2*64; i += 256){
    int kk = i >> 6, j2 = i & 63;
    sW34[i] = make_float4(Wtcat[(128+4*kk+0)*64 + j2]*RS136,
                          Wtcat[(128+4*kk+1)*64 + j2]*RS136,
                          Wtcat[(128+4*kk+2)*64 + j2]*RS136,
                          Wtcat[(128+4*kk+3)*64 + j2]*RS136);
  }
  for (int i = threadIdx.x; i < 16*64; i += 256){
    int kk = i >> 6, j2 = i & 63;
    swij4[i] = make_float4(Wtij[(4*kk+0)*64 + j2], Wtij[(4*kk+1)*64 + j2],
                           Wtij[(4*kk+2)*64 + j2], Wtij[(4*kk+3)*64 + j2]);
  }
  for (int i = threadIdx.x; i < 16*24; i += 256){
    int kk = i / 24, c = i - kk*24;
    sw04[i] = make_float4(Wt0[(4*kk+0)*24 + c], Wt0[(4*kk+1)*24 + c],
                          Wt0[(4*kk+2)*24 + c], Wt0[(4*kk+3)*24 + c]);
  }
  __syncthreads();
  const int j = threadIdx.x & 63, lw = threadIdx.x >> 6;
  const float gj = lg[j], bj = lb[j];
  const int jc = (j < 24) ? j : 0;
  int wid = blockIdx.x*4 + lw;
  int nw  = gridDim.x*4;
  for (int p = wid; p < N_EDGES/4; p += nw){
    const int eb = p*4;
    int4 cv = *(const int4*)(ec + eb);
    int4 nv = *(const int4*)(en + eb);
    int ccs[4], nns[4];
    ccs[0] = __builtin_amdgcn_readfirstlane(cv.x);
    ccs[1] = __builtin_amdgcn_readfirstlane(cv.y);
    ccs[2] = __builtin_amdgcn_readfirstlane(cv.z);
    ccs[3] = __builtin_amdgcn_readfirstlane(cv.w);
    nns[0] = __builtin_amdgcn_readfirstlane(nv.x);
    nns[1] = __builtin_amdgcn_readfirstlane(nv.y);
    nns[2] = __builtin_amdgcn_readfirstlane(nv.z);
    nns[3] = __builtin_amdgcn_readfirstlane(nv.w);
    // phase 1: gather + phi GEMV + LN
    float a[4], hh[4];
    #pragma unroll
    for (int x = 0; x < 4; x++){
      a[x]  = P0[(long)ccs[x]*152 + j] + P0[(long)nns[x]*152 + 64 + j];
      hh[x] = P0[(long)nns[x]*152 + 128 + jc];
    }
    const float4* ph = (const float4*)(phi + (long)eb*D_RAD);
    #pragma unroll
    for (int kk = 0; kk < 2; kk++){
      float4 p0=ph[kk], p1=ph[2+kk], p2=ph[4+kk], p3=ph[6+kk];
      float4 u4 = sW34[kk*64 + j];
      #pragma unroll
      for (int i = 0; i < 4; i++){
        float u = f4g(u4, i);
        a[0]+=f4g(p0,i)*u; a[1]+=f4g(p1,i)*u; a[2]+=f4g(p2,i)*u; a[3]+=f4g(p3,i)*u;
      }
    }
    #pragma unroll
    for (int x = 0; x < 4; x++){
      float acc = a[x];
      float mu = wave_sum(acc) * (1.f/64.f);
      float va = wave_sum(acc*acc) * (1.f/64.f) - mu*mu;
      float t = (acc - mu) * rsqrtf(va + 1e-5f) * gj + bj;
      T[(long)(eb+x)*LAT + j] = t;
      tst[lw][x][j] = t;
    }
    // phase 2 (tst same-wave DS: in-order, no fence needed)
    float eo[4]={0,0,0,0}, av[4]={0,0,0,0};
    #pragma unroll 2
    for (int kk = 0; kk < 16; kk++){
      float4 tv0 = *(const float4*)&tst[lw][0][kk*4];
      float4 tv1 = *(const float4*)&tst[lw][1][kk*4];
      float4 tv2 = *(const float4*)&tst[lw][2][kk*4];
      float4 tv3 = *(const float4*)&tst[lw][3][kk*4];
      float4 u4 = swij4[kk*64 + j];
      float4 w4 = sw04[kk*24 + jc];
      #pragma unroll
      for (int i = 0; i < 4; i++){
        float u = f4g(u4, i), w = f4g(w4, i);
        eo[0]+=f4g(tv0,i)*u; av[0]+=f4g(tv0,i)*w;
        eo[1]+=f4g(tv1,i)*u; av[1]+=f4g(tv1,i)*w;
        eo[2]+=f4g(tv2,i)*u; av[2]+=f4g(tv2,i)*w;
        eo[3]+=f4g(tv3,i)*u; av[3]+=f4g(tv3,i)*w;
      }
    }
    float w0s[4];
    #pragma unroll
    for (int x = 0; x < 4; x++){
      edge_out[(long)(eb+x)*LAT + j] = eo[x] * 0.125f;
      w0s[x] = av[x] * hh[x] * 0.125f;
    }
    #pragma unroll
    for (int x = 0; x < 4; x++){
      #pragma unroll
      for (int rep = 0; rep < 2; rep++){
        int tt = j + rep*64;
        int m = tt/9, d = tt - (tt/9)*9;
        int wi = (tt < 72) ? (irrep_of(d)*NHEAD + m) : 0;
        float wv = __shfl(w0s[x], wi);
        if (tt < 72){
          atomicAdd(&Xacc[ccs[x]*72 + tt], sph[(long)(eb+x)*D_SPH + d] * wv);
        }
      }
    }
  }
}

// K5: X = so3_norm(Xacc); also zero/init per-layer accumulators (hacc/asum/amax/Xacc)
__global__ void k_node_X0(float* __restrict__ Xacc, float* __restrict__ X,
                          float* __restrict__ hacc, float* __restrict__ asum,
                          float* __restrict__ amax){
  int n = blockIdx.x*(blockDim.x >> 6) + (threadIdx.x >> 6);
  int j = threadIdx.x & 63;
  if (n >= N_NODES) return;
  float x0 = Xacc[n*72 + j];
  float x1 = (j < 8) ? Xacc[n*72 + 64 + j] : 0.f;
  float s0 = 0.f, s1 = 0.f, s2 = 0.f;
  { int d = j % 9; int k3 = irrep_of(d);
    if (k3 == 0) s0 = x0*x0; else if (k3 == 1) s1 = x0*x0; else s2 = x0*x0; }
  if (j < 8){ int d = (64 + j) % 9; int k3 = irrep_of(d);
    if (k3 == 0) s0 += x1*x1; else if (k3 == 1) s1 += x1*x1; else s2 += x1*x1; }
  s0 = wave_sum(s0); s1 = wave_sum(s1); s2 = wave_sum(s2);
  float sa = rsqrtf(s0*0.125f + 1e-5f), sb = rsqrtf(s1*0.125f + 1e-5f), sc = rsqrtf(s2*0.125f + 1e-5f);
  { int d = j % 9; int k3 = irrep_of(d);
    X[n*72 + j] = x0 * (k3==0 ? sa : (k3==1 ? sb : sc)); }
  if (j < 8){ int d = (64 + j) % 9; int k3 = irrep_of(d);
    X[n*72 + 64 + j] = x1 * (k3==0 ? sa : (k3==1 ? sb : sc)); }
  // reset accumulators for layer 0
  Xacc[n*72 + j] = 0.f;
  if (j < 8) Xacc[n*72 + 64 + j] = 0.f;
  hacc[n*LAT + j] = 0.f;
  if (j < 8){ asum[n*NHEAD + j] = 0.f; amax[n*NHEAD + j] = __uint_as_float(0xff800000u); }
}

// K6: attention logits + running max. Q = t@Wq; K gathered from Hk.
// T rows staged: ONE coalesced load/group -> LDS -> wave-uniform b128 broadcast
// reads (replaces 64 uniform VMEM loads). LDS 36.9KB -> 4 blk/CU.
__global__ void __launch_bounds__(256,4) k_att(const float* __restrict__ T, const float* __restrict__ Hk,
                     const float* __restrict__ Wq,
                     const int* __restrict__ ec, const int* __restrict__ en,
                     float* __restrict__ att, float* __restrict__ attmax){
  __shared__ float4 sqa[16*64], sqb[16*64];
  __shared__ float stA[4][4][64];
  for (int i = threadIdx.x; i < 16*64; i += 256){
    int kk = i >> 6, j2 = i & 63;
    sqa[i] = make_float4(Wq[(4*kk+0)*128 + j2], Wq[(4*kk+1)*128 + j2],
                         Wq[(4*kk+2)*128 + j2], Wq[(4*kk+3)*128 + j2]);
    sqb[i] = make_float4(Wq[(4*kk+0)*128 + 64 + j2], Wq[(4*kk+1)*128 + 64 + j2],
                         Wq[(4*kk+2)*128 + 64 + j2], Wq[(4*kk+3)*128 + 64 + j2]);
  }
  __syncthreads();
  const int j = threadIdx.x & 63, lw = threadIdx.x >> 6;
  int wid = blockIdx.x*4 + lw;
  int nw  = gridDim.x*4;
  for (int p = wid; p < N_EDGES/4; p += nw){
    const int eb = p*4;
    int4 cv = *(const int4*)(ec + eb);
    int4 nv = *(const int4*)(en + eb);
    int ccs[4], nns[4];
    ccs[0] = __builtin_amdgcn_readfirstlane(cv.x);
    ccs[1] = __builtin_amdgcn_readfirstlane(cv.y);
    ccs[2] = __builtin_amdgcn_readfirstlane(cv.z);
    ccs[3] = __builtin_amdgcn_readfirstlane(cv.w);
    nns[0] = __builtin_amdgcn_readfirstlane(nv.x);
    nns[1] = __builtin_amdgcn_readfirstlane(nv.y);
    nns[2] = __builtin_amdgcn_readfirstlane(nv.z);
    nns[3] = __builtin_amdgcn_readfirstlane(nv.w);
    // stage 4 T-rows: one coalesced dwordx4 per lane covers all 256 floats
    {
      float4 tl = *(const float4*)(T + (long)eb*LAT + j*4);
      *(float4*)&stA[lw][j >> 4][(j & 15)*4] = tl;
    }
    float ha[4], hb[4];
    #pragma unroll
    for (int x = 0; x < 4; x++){
      ha[x] = Hk[(long)nns[x]*128 + j];
      hb[x] = Hk[(long)nns[x]*128 + 64 + j];
    }
    float qa[4]={0,0,0,0}, qb[4]={0,0,0,0};
    #pragma unroll 2
    for (int kk = 0; kk < 16; kk++){
      float4 tv[4];
      tv[0] = *(const float4*)&stA[lw][0][kk*4];
      tv[1] = *(const float4*)&stA[lw][1][kk*4];
      tv[2] = *(const float4*)&stA[lw][2][kk*4];
      tv[3] = *(const float4*)&stA[lw][3][kk*4];
      float4 wa = sqa[kk*64 + j];
      float4 wb = sqb[kk*64 + j];
      #pragma unroll
      for (int i = 0; i < 4; i++){
        float q0 = f4g(wa, i), q1 = f4g(wb, i);
        #pragma unroll
        for (int x = 0; x < 4; x++){
          float tx = f4g(tv[x], i);
          qa[x] += tx*q0; qb[x] += tx*q1;
        }
      }
    }
    float pa[4], pb[4];
    #pragma unroll
    for (int x = 0; x < 4; x++){ pa[x] = qa[x]*ha[x]; pb[x] = qb[x]*hb[x]; }
    #pragma unroll
    for (int off = 8; off; off >>= 1){
      #pragma unroll
      for (int x = 0; x < 4; x++){
        pa[x] += __shfl_xor(pa[x], off);
        pb[x] += __shfl_xor(pb[x], off);
      }
    }
    if ((j & 15) == 0){
      int m = j >> 4;
      #pragma unroll
      for (int x = 0; x < 4; x++){
        float A = 4.f*pa[x], B = 4.f*pb[x];
        att[(long)(eb+x)*NHEAD + m] = A;
        att[(long)(eb+x)*NHEAD + 4 + m] = B;
        atomicMaxF(&attmax[ccs[x]*NHEAD + m], A);
        atomicMaxF(&attmax[ccs[x]*NHEAD + 4 + m], B);
      }
    }
  }
}

// K7: env = (t@Wrs[:216]) * Hw[nb]; hacc/asum/Xacc scatter in one pass.
// 1024 thr (16 waves) / 1 blk/CU. T rows staged via ONE coalesced load ->
// LDS broadcast (replaces 64 uniform VMEM loads/group — the latency source).
// senv k3-stride 72 (conflict-free dq reads). LDS 155648 B.
__global__ void __launch_bounds__(1024,4) k_env(
    const float* __restrict__ T, const float* __restrict__ Hw,
    const float* __restrict__ X,
    const float* __restrict__ Wrs,
    const float* __restrict__ sph,
    const float* __restrict__ att, const float* __restrict__ attmax,
    const int* __restrict__ ec, const int* __restrict__ en,
    float* __restrict__ hacc, float* __restrict__ asum,
    float* __restrict__ Xacc){
  __shared__ float srs[64*216];
  __shared__ float senv[16][4][240];
  __shared__ float sxn[16][4][80];
  __shared__ float sev[16][32];
  __shared__ float stT[16][4][64];
  for (int i = threadIdx.x; i < 64*216; i += 1024){
    int k = i / 216, c = i - k*216;
    srs[i] = Wrs[k*GEN_W + c];
  }
  __syncthreads();
  const int j = threadIdx.x & 63, lw = threadIdx.x >> 6;
  int wpos = 0;
  if (j < 54){
    int c0 = 4*j;
    wpos = (c0 < 24) ? c0 : 24 + ((c0-24) >> 6)*72 + ((c0-24) & 63);
  }
  const int d0 = j - (j/9)*9, m0 = j/9;   // rep0: tt=j
  const int d1 = 1 + j, m1 = 7;            // rep1: tt=64+j (j<8)
  int wid = blockIdx.x*16 + lw;
  int nw  = gridDim.x*16;
  for (int p = wid; p < N_EDGES/4; p += nw){
    const int eb = p*4;
    int4 cv = *(const int4*)(ec + eb);
    int4 nv = *(const int4*)(en + eb);
    int ccs[4], nns[4];
    ccs[0] = __builtin_amdgcn_readfirstlane(cv.x);
    ccs[1] = __builtin_amdgcn_readfirstlane(cv.y);
    ccs[2] = __builtin_amdgcn_readfirstlane(cv.z);
    ccs[3] = __builtin_amdgcn_readfirstlane(cv.w);
    nns[0] = __builtin_amdgcn_readfirstlane(nv.x);
    nns[1] = __builtin_amdgcn_readfirstlane(nv.y);
    nns[2] = __builtin_amdgcn_readfirstlane(nv.z);
    nns[3] = __builtin_amdgcn_readfirstlane(nv.w);
    // stage 4 T-rows: one coalesced dwordx4 per lane (256 floats total)
    {
      float4 tl = *(const float4*)(T + (long)eb*LAT + j*4);
      *(float4*)&stT[lw][j >> 4][(j & 15)*4] = tl;
    }
    // stage X rows (coalesced) for the d_eq gathers
    #pragma unroll
    for (int x = 0; x < 4; x++){
      const float* Xr = X + (long)nns[x]*72;
      sxn[lw][x][j] = Xr[j];
      if (j < 8) sxn[lw][x][64 + j] = Xr[64 + j];
    }
    float4 aT[4];
    #pragma unroll
    for (int x = 0; x < 4; x++) aT[x] = make_float4(0.f,0.f,0.f,0.f);
    if (j < 54){
      #pragma unroll 2
      for (int kk = 0; kk < 16; kk++){
        float4 tv[4];
        tv[0] = *(const float4*)&stT[lw][0][kk*4];
        tv[1] = *(const float4*)&stT[lw][1][kk*4];
        tv[2] = *(const float4*)&stT[lw][2][kk*4];
        tv[3] = *(const float4*)&stT[lw][3][kk*4];
        #pragma unroll
        for (int i = 0; i < 4; i++){
          const float4 r4 = *(const float4*)(srs + (kk*4+i)*216 + j*4);
          #pragma unroll
          for (int x = 0; x < 4; x++){
            float tx = f4g(tv[x], i);
            aT[x].x += tx*r4.x; aT[x].y += tx*r4.y; aT[x].z += tx*r4.z; aT[x].w += tx*r4.w;
          }
        }
      }
      #pragma unroll
      for (int x = 0; x < 4; x++){
        const float4 hw4 = *(const float4*)(Hw + (long)nns[x]*216 + j*4);
        float4 ev4;
        ev4.x = aT[x].x * hw4.x;
        ev4.y = aT[x].y * hw4.y;
        ev4.z = aT[x].z * hw4.z;
        ev4.w = aT[x].w * hw4.w;
        *(float4*)&senv[lw][x][wpos] = ev4;
      }
    }
    if (j < 32){
      int x = j >> 3, m = j & 7;
      int cc = ccs[x];
      float ev = __expf(att[(long)(eb+x)*NHEAD + m] - attmax[cc*NHEAD + m]);
      sev[lw][j] = ev;
      atomicAdd(&asum[cc*NHEAD + m], ev);
    }
    // hacc from senv cols 0..63 (same-wave DS in-order)
    #pragma unroll
    for (int x = 0; x < 4; x++){
      atomicAdd(&hacc[ccs[x]*LAT + j], senv[lw][x][j]);
    }
    // scatter: (d_sph + d_eq) * exp
    #pragma unroll
    for (int x = 0; x < 4; x++){
      const long e = eb + x;
      const int cc = ccs[x];
      {
        int k3 = irrep_of(d0);
        float ds = sph[e*D_SPH + d0] * senv[lw][x][k3*8 + m0];
        float dq = 0.f;
        #pragma unroll
        for (int i = 0; i < 8; i++) dq += sxn[lw][x][i*9 + d0] * senv[lw][x][24 + k3*72 + i*8 + m0];
        float val = (ds + dq*RS8) * sev[lw][x*8 + m0];
        atomicAdd(&Xacc[cc*72 + j], val);
      }
      if (j < 8){
        int k3 = irrep_of(d1);
        float ds = sph[e*D_SPH + d1] * senv[lw][x][k3*8 + m1];
        float dq = 0.f;
        #pragma unroll
        for (int i = 0; i < 8; i++) dq += sxn[lw][x][i*9 + d1] * senv[lw][x][24 + k3*72 + i*8 + m1];
        float val = (ds + dq*RS8) * sev[lw][x*8 + m1];
        atomicAdd(&Xacc[cc*72 + 64 + j], val);
      }
    }
  }
}

// K8: h = LN(h+hacc); X = so3_norm(X + Xacc/(attsum+1e-12)); reset accumulators
__global__ void k_node_upd(float* __restrict__ hacc, float* __restrict__ attsum,
                           float* __restrict__ Xacc, float* __restrict__ amax,
                           const float* __restrict__ lg, const float* __restrict__ lb,
                           float* __restrict__ h, float* __restrict__ X){
  int n = blockIdx.x*(blockDim.x >> 6) + (threadIdx.x >> 6);
  int j = threadIdx.x & 63;
  if (n >= N_NODES) return;
  float hv = h[n*LAT + j] + hacc[n*LAT + j];
  float mu = wave_sum(hv) * (1.f/64.f);
  float va = wave_sum(hv*hv) * (1.f/64.f) - mu*mu;
  h[n*LAT + j] = (hv - mu) * rsqrtf(va + 1e-5f) * lg[j] + lb[j];

  float x0, x1 = 0.f;
  float s0 = 0.f, s1 = 0.f, s2 = 0.f;
  { int m = j/9, d = j - m*9;
    x0 = X[n*72 + j] + Xacc[n*72 + j] / (attsum[n*NHEAD + m] + 1e-12f);
    int k3 = irrep_of(d);
    if (k3 == 0) s0 = x0*x0; else if (k3 == 1) s1 = x0*x0; else s2 = x0*x0; }
  if (j < 8){ int tt = 64 + j; int m = tt/9, d = tt - m*9;
    x1 = X[n*72 + tt] + Xacc[n*72 + tt] / (attsum[n*NHEAD + m] + 1e-12f);
    int k3 = irrep_of(d);
    if (k3 == 0) s0 += x1*x1; else if (k3 == 1) s1 += x1*x1; else s2 += x1*x1; }
  s0 = wave_sum(s0); s1 = wave_sum(s1); s2 = wave_sum(s2);
  float sa = rsqrtf(s0*0.125f + 1e-5f), sb = rsqrtf(s1*0.125f + 1e-5f), sc = rsqrtf(s2*0.125f + 1e-5f);
  { int d = j % 9; int k3 = irrep_of(d);
    X[n*72 + j] = x0 * (k3==0 ? sa : (k3==1 ? sb : sc)); }
  if (j < 8){ int d = (64 + j) % 9; int k3 = irrep_of(d);
    X[n*72 + 64 + j] = x1 * (k3==0 ? sa : (k3==1 ? sb : sc)); }
  // reset accumulators for next layer
  Xacc[n*72 + j] = 0.f;
  if (j < 8) Xacc[n*72 + 64 + j] = 0.f;
  hacc[n*LAT + j] = 0.f;
  if (j < 8){ attsum[n*NHEAD + j] = 0.f; amax[n*NHEAD + j] = __uint_as_float(0xff800000u); }
}

// K9: w = h@W_hemb/8 -> (3,8,64); Xo = eq_linear(X,w); node_out
__global__ void k_node_out(const float* __restrict__ h, const float* __restrict__ X,
                           const float* __restrict__ Whemb,
                           float* __restrict__ out){
  __shared__ float sx[4][72];
  int n = blockIdx.x*(blockDim.x >> 6) + (threadIdx.x >> 6);
  int j = threadIdx.x & 63;
  int lw = threadIdx.x >> 6;
  if (n >= N_NODES) return;
  float hv = h[n*LAT + j];
  float wv[24];
  #pragma unroll
  for (int i = 0; i < 24; i++) wv[i] = 0.f;
  #pragma unroll 4
  for (int c = 0; c < LAT; c++){
    float hc = __shfl(hv, c);
    #pragma unroll
    for (int ki = 0; ki < 24; ki++)
      wv[ki] += hc * Whemb[c*1536 + ki*64 + j];
  }
  sx[lw][j] = X[n*72 + j];
  if (j < 8) sx[lw][64 + j] = X[n*72 + 64 + j];
  #pragma unroll
  for (int d = 0; d < 9; d++){
    int k3 = irrep_of(d);
    float acc = 0.f;
    #pragma unroll
    for (int i = 0; i < 8; i++) acc += sx[lw][i*9 + d] * wv[k3*8 + i];
    acc *= 0.125f * RS8;
    int pos;
    if (d == 0)      pos = n*576 + j;
    else if (d < 4)  pos = n*576 + 64  + j*3 + (d - 1);
    else             pos = n*576 + 256 + j*5 + (d - 4);
    out[pos] = acc;
  }
}

// ---- workspace layout (floats) — total 26.56M floats = 106.2 MB ----
static const long O_T    = 0;          // 20.48M  (E*64)
static const long O_ATT  = 20480000;   // 2.56M   (E*8) ; prologue pn/pc/mn/P0 alias here
static const long O_H0   = 23040000;   // 640k
static const long O_H    = 23680000;   // 640k
static const long O_X    = 24320000;   // 720k
static const long O_XACC = 25040000;   // 720k
static const long O_HACC = 25760000;   // 640k
static const long O_AMAX = 26400000;   // 80k
static const long O_ASUM = 26480000;   // 80k

extern "C" void kernel_launch(void* const* d_in, const int* in_sizes, int n_in,
                              void* d_out, int out_size, void* d_ws, size_t ws_size,
                              hipStream_t stream) {
  const float* na    = (const float*)d_in[0];
  const float* phi   = (const float*)d_in[1];
  const float* sph   = (const float*)d_in[2];
  const float* Wn    = (const float*)d_in[4];
  const float* Wc    = (const float*)d_in[5];
  const float* Wcat  = (const float*)d_in[6];
  const float* We    = (const float*)d_in[7];
  const float* ln0g  = (const float*)d_in[8];
  const float* ln0b  = (const float*)d_in[9];
  const float* lneg  = (const float*)d_in[10];
  const float* lneb  = (const float*)d_in[11];
  const float* Wtcat = (const float*)d_in[12];
  const float* Wt0   = (const float*)d_in[13];
  const float* Wh0   = (const float*)d_in[14];
  const float* Wrs   = (const float*)d_in[15];
  const float* Whj   = (const float*)d_in[16];
  const float* lnlg  = (const float*)d_in[17];
  const float* lnlb  = (const float*)d_in[18];
  const float* Wq    = (const float*)d_in[19];
  const float* Wk    = (const float*)d_in[20];
  const float* Whemb = (const float*)d_in[21];
  const float* Wtij  = (const float*)d_in[22];
  const int* ec = (const int*)d_in[23];
  const int* en = (const int*)d_in[24];

  float* ws   = (float*)d_ws;
  float* T    = ws + O_T;
  float* att  = ws + O_ATT;
  float* h0   = ws + O_H0;
  float* h    = ws + O_H;
  float* X    = ws + O_X;
  float* Xacc = ws + O_XACC;
  float* hacc = ws + O_HACC;
  float* amax = ws + O_AMAX;
  float* asum = ws + O_ASUM;
  // prologue-only buffers alias the att region (dead before k_att runs)
  float* pn   = att;
  float* pc   = att + 640000;
  float* mn   = att + 1280000;
  float* P0   = att;               // 1.52M, written after pn/pc/mn are dead

  float* out      = (float*)d_out;
  float* edge_out = out + (long)N_NODES*576;
  // per-layer node precomputes scratch in node_out region (written only at end)
  float* Hk = out;                 // 1.28M
  float* Hw = out + 1280000;       // 2.16M

  k_node_proj<<<(N_NODES*64)/256, 256, 0, stream>>>(na, Wn, Wc, pn, pc, mn, Xacc);
  k_edge_msg<<<1024, 256, 0, stream>>>(phi, We, ec, en, pn, mn);
  k_node_h<<<N_NODES/4, 256, 0, stream>>>(pc, mn, Wcat, ln0g, ln0b, h0, h);
  k_pre0<<<256, 256, 0, stream>>>(h0, Wtcat, Wh0, P0);
  k_tij<<<1024, 256, 0, stream>>>(P0, phi, sph, Wtcat, lneg, lneb, Wtij, Wt0,
                                  ec, en, T, Xacc, edge_out);
  k_node_X0<<<N_NODES/4, 256, 0, stream>>>(Xacc, X, hacc, asum, amax);

  for (int l = 0; l < NL; l++){
    k_node_mm<128><<<512, 256, 0, stream>>>(h, Wk + l*64*128, 128, 1.f, Hk);
    k_node_mm<216><<<512, 256, 0, stream>>>(h, Whj + (long)l*64*GEN_W, GEN_W, 0.125f, Hw);
    k_att<<<1024, 256, 0, stream>>>(T, Hk, Wq + l*64*128, ec, en, att, amax);
    k_env<<<256, 1024, 0, stream>>>(T, Hw, X, Wrs + (long)l*64*GEN_W, sph,
                                    att, amax, ec, en, hacc, asum, Xacc);
    k_node_upd<<<N_NODES/4, 256, 0, stream>>>(hacc, asum, Xacc, amax,
                                              lnlg + l*64, lnlb + l*64, h, X);
  }

  k_node_out<<<N_NODES/4, 256, 0, stream>>>(h, X, Whemb, out);
}